// Round 7
// baseline (585.904 us; speedup 1.0000x reference)
//
#include <hip/hip_runtime.h>
#include <hip/hip_bf16.h>
#include <math.h>

#define L_SZ 1024
#define STRIDE_ 32
#define WIN 8
#define PNUM 31
#define NPATCH 31744   // 1024 batches x 31 patches
#define SGRID 768      // 256 CU x 3 blocks/CU
#define SSTEP_B 24     // SGRID = 24*PNUM + 24 -> (b,p) += (24,24) with carry
#define SSTEP_P 24

// LDS row strides (in shorts). dword strides = 36/68 = 4 mod 32 -> 2-way banks (free).
#define X1TS 72
#define CAS  136

typedef __attribute__((ext_vector_type(8))) short short8;
typedef __attribute__((ext_vector_type(4))) short short4v;
typedef __attribute__((ext_vector_type(4))) float f32x4;

#define MFMA16(a, b, c) __builtin_amdgcn_mfma_f32_16x16x32_bf16(a, b, c, 0, 0, 0)

__device__ __forceinline__ float sigf(float x) { return 1.0f / (1.0f + __expf(-x)); }
__device__ __forceinline__ float tanhfast(float x) {
    float ax = fabsf(x);
    float t = __expf(-2.0f * ax);
    return copysignf((1.0f - t) / (1.0f + t), x);
}
__device__ __forceinline__ short f2bf(float f) {
    __hip_bfloat16 h = __float2bfloat16(f);   // RNE
    return *reinterpret_cast<short*>(&h);
}
__device__ __forceinline__ float bf2f(short s) {
    __hip_bfloat16 h = *reinterpret_cast<__hip_bfloat16*>(&s);
    return __bfloat162float(h);
}
__device__ __forceinline__ float f4c(float4 v, int k) {
    return k == 0 ? v.x : (k == 1 ? v.y : (k == 2 ? v.z : v.w));
}
__device__ __forceinline__ void fma4(float4& acc, float s, float4 v) {
    acc.x += s * v.x; acc.y += s * v.y; acc.z += s * v.z; acc.w += s * v.w;
}

// ---------------------------------------------------------------------------
// adjn[i][j] = sigmoid(ew[i][j]) * mask(|i-j|<=8, i!=j) * deg_inv[i]
// ---------------------------------------------------------------------------
__global__ void adj_kernel(const float* __restrict__ ew, float* __restrict__ adjn) {
    int i = threadIdx.x;
    if (i >= 64) return;
    float sum = 0.f;
    for (int j = 0; j < 64; ++j) {
        int d = i - j; d = d < 0 ? -d : d;
        float a = (d <= WIN && d != 0) ? sigf(ew[i * 64 + j]) : 0.f;
        sum += a;
    }
    float dinv = (sum > 0.f) ? 1.0f / sum : 0.f;
    for (int j = 0; j < 64; ++j) {
        int d = i - j; d = d < 0 ? -d : d;
        float a = (d <= WIN && d != 0) ? sigf(ew[i * 64 + j]) : 0.f;
        adjn[i * 64 + j] = a * dinv;
    }
}

// ---------------------------------------------------------------------------
// prep (unchanged from R15):
//   blocks   0..127 : Wih0T | 128..383 : Wih1T | 384..393 : sage frags
//   blocks 394..457 : Whh0 frags hi/lo | 458..521 : Whh1 frags hi/lo
// ---------------------------------------------------------------------------
__global__ void prep_kernel(const float* __restrict__ Wih0, const float* __restrict__ Whh0,
                            const float* __restrict__ Wih1, const float* __restrict__ Whh1,
                            const float* __restrict__ adjn,
                            const float* __restrict__ Ws2, const float* __restrict__ Wn2,
                            float* __restrict__ Wih0T, float* __restrict__ Wih1T,
                            short* __restrict__ adjfG, short* __restrict__ wcatfG,
                            short* __restrict__ whhf0G, short* __restrict__ whhf1G) {
    int bid = blockIdx.x, tid = threadIdx.x;
    if (bid < 128) {
        int e = bid * 256 + tid;
        int k = e >> 9, j = e & 511;
        Wih0T[e] = Wih0[j * 64 + k];
        return;
    }
    if (bid < 384) {
        int e = (bid - 128) * 256 + tid;
        int k = e >> 9, j = e & 511;
        Wih1T[e] = Wih1[j * 128 + k];
        return;
    }
    if (bid < 394) {
        int t = (bid - 384) * 256 + tid;
        if (t >= 2432) return;
        int f = t >> 6, l = t & 63;
        int q = l >> 4, l15 = l & 15;
        short8 v;
        if (f < 6) {
            const int ntT[6] = {0, 1, 1, 2, 2, 3};
            const int ksT[6] = {0, 0, 1, 0, 1, 1};
            int row = l15 + 16 * ntT[f], col = 8 * q + 32 * ksT[f];
            #pragma unroll
            for (int e = 0; e < 8; ++e)
                v[e] = f2bf(adjn[row * 64 + col + e]);
            *(short8*)(adjfG + ((size_t)f * 64 + l) * 8) = v;
        } else {
            int fi = f - 6;
            int isLo = fi >= 16;
            int ff = isLo ? fi - 16 : fi;
            int nt = ff >> 2, ks = ff & 3;
            int oo = l15 + 16 * nt;
            #pragma unroll
            for (int e = 0; e < 8; ++e) {
                int k = 32 * ks + 8 * q + e;
                float src = (k < 64) ? Ws2[oo * 64 + k] : Wn2[oo * 64 + (k - 64)];
                short hi = f2bf(src);
                v[e] = isLo ? f2bf(src - bf2f(hi)) : hi;
            }
            *(short8*)(wcatfG + ((size_t)fi * 64 + l) * 8) = v;
        }
        return;
    }
    {
        int layer = (bid < 458) ? 0 : 1;
        int base = layer ? 458 : 394;
        const float* Whh = layer ? Whh1 : Whh0;
        short* dst = layer ? whhf1G : whhf0G;
        int t = (bid - base) * 256 + tid;    // 0..16383
        int frag = t >> 6, l = t & 63;
        int hl = frag & 1, ks = (frag >> 1) & 3, NT = frag >> 3;
        int g = NT * 16 + (l & 15);
        int kbase = ks * 32 + (l >> 4) * 8;
        short8 v;
        #pragma unroll
        for (int e = 0; e < 8; ++e) {
            float src = Whh[(size_t)g * 128 + kbase + e];
            short hi = f2bf(src);
            v[e] = hl ? f2bf(src - bf2f(hi)) : hi;
        }
        *(short8*)(dst + (size_t)t * 8) = v;
    }
}

// ---------------------------------------------------------------------------
// Persistent fused SAGE, bf16 MFMA.
// R22: arch-VGPR diet to reach 3 waves/SIMD. Residency model fit across
// R15/R17/R18/R20/R21: compiler always allocates a fixed 64-reg accumulator
// block for MFMA kernels; waves/SIMD = floor(512/(archVGPR+64)). R21's 116
// arch -> 180 total -> 2 waves/SIMD -> 2 blocks/CU + tail (occ 18.6%).
// Target arch <= 106 (total <= 170 -> 3 waves/SIMD -> 3 blocks/CU, 768-grid
// tail-free). Cuts vs R21 (zero math changes):
//  (a) x0 register prefetch removed (nxa/nxb + 64-bit addr temps, ~10 regs);
//      with 12 waves/CU the load latency is TLP-hidden instead.
//  (b) per-iter m/PNUM, m%PNUM -> incremental (b,p) carry: p+=24;b+=24;
//      if(p>=31){p-=31;++b;} (768 = 24*31+24). Kills magic-mul temps.
//  (c) feats address via incremental offset.
// LDS 44,032 B (single x1T + double cat) unchanged; 2 barriers/iter.
// ---------------------------------------------------------------------------
__launch_bounds__(256, 2)
__global__ void sage_mfma(const float* __restrict__ I, const float* __restrict__ Q,
                          const float* __restrict__ adjn,
                          const float* __restrict__ Wn1, const float* __restrict__ bn1,
                          const float* __restrict__ Ws1, const float* __restrict__ bs1,
                          const float* __restrict__ bn2, const float* __restrict__ bs2,
                          const short* __restrict__ adjfG, const short* __restrict__ wcatfG,
                          float* __restrict__ feats) {
    __shared__ __align__(16) short s_x1T[64 * X1TS];     // x1^T [o][i] bf16 (single)
    __shared__ __align__(16) short s_cat[2][64 * CAS];   // [i][x1|n1] bf16 (double)

    const int tid = threadIdx.x;
    const int w = tid >> 6, l = tid & 63, q = l >> 4, l15 = l & 15;

    // adj frags for THIS wave's i-tile (band): w0:{ks0}, w1/w2:{ks0,ks1}, w3:{ks1}
    const bool hasKs0 = (w <= 2);
    const bool hasKs1 = (w >= 1);
    const int idx0 = (w == 0) ? 0 : (w == 1 ? 1 : 3);    // frag idx for (nt=w, ks=0)
    const int idx1 = (w == 1) ? 2 : (w == 2 ? 4 : 5);    // frag idx for (nt=w, ks=1)
    short8 adjB0 = {}, adjB1 = {};
    if (hasKs0) adjB0 = *(const short8*)(adjfG + ((size_t)idx0 * 64 + l) * 8);
    if (hasKs1) adjB1 = *(const short8*)(adjfG + ((size_t)idx1 * 64 + l) * 8);

    // weight frags for THIS wave's o-tile (nt = w): 8 frags = 32 VGPRs
    short8 whf[4], wlf[4];
    #pragma unroll
    for (int ks = 0; ks < 4; ++ks) {
        whf[ks] = *(const short8*)(wcatfG + ((size_t)(w * 4 + ks) * 64 + l) * 8);
        wlf[ks] = *(const short8*)(wcatfG + ((size_t)(w * 4 + ks + 16) * 64 + l) * 8);
    }
    // bias for this wave's output channel (loop-invariant)
    const int oo = l15 + 16 * w;
    const float bo = bs2[oo] + bn2[oo];

    // adjn band in registers: lane l = row i; zeros outside [0,64)
    float areg[17];
    #pragma unroll
    for (int d = 0; d < 17; ++d) {
        int j = l + d - WIN;
        areg[d] = (j >= 0 && j < 64) ? adjn[l * 64 + j] : 0.f;
    }

    // incremental patch coords: m = b*PNUM + p
    int m = blockIdx.x;
    int b = m / PNUM, p = m % PNUM;      // once, outside the loop

    int pb = 0;
    while (m < NPATCH) {
        // x0 load (lane l holds column i = l; same in all 4 waves, L1-broadcast)
        const int xoff = b * L_SZ + p * STRIDE_ + l;
        const float x0a = I[xoff];
        const float x0b = Q[xoff];

        short* __restrict__ cat = s_cat[pb];

        // ---- Phase 1: n0 via shuffles, x1 = relu(...) ----
        {
            // fixed-trip window; out-of-band areg == 0.0f exactly
            float n0a = 0.f, n0b = 0.f;
            #pragma unroll
            for (int d = 0; d < 17; ++d) {
                int j = l + d - WIN;
                float xa = __shfl(x0a, j, 64);
                float xb = __shfl(x0b, j, 64);
                n0a += areg[d] * xa;
                n0b += areg[d] * xb;
            }
            union { short s[16]; short8 v[2]; } pk;
            #pragma unroll
            for (int t = 0; t < 16; ++t) {
                int o = w * 16 + t;
                float2 wsv = ((const float2*)Ws1)[o];
                float2 wnv = ((const float2*)Wn1)[o];
                float v = bs1[o] + bn1[o] + wsv.x * x0a + wsv.y * x0b
                                          + wnv.x * n0a + wnv.y * n0b;
                v = fmaxf(v, 0.f);
                short bv = f2bf(v);
                s_x1T[o * X1TS + l] = bv;
                pk.s[t] = bv;
            }
            *(short8*)&cat[l * CAS + w * 16]     = pk.v[0];
            *(short8*)&cat[l * CAS + w * 16 + 8] = pk.v[1];
        }
        __syncthreads();   // barrier 1: x1T/cat(x1) visible to all waves

        // ---- MFMA#1: n1^T for i-tile w. A = x1T o-tiles, B = adj cols. ----
        #pragma unroll
        for (int ot = 0; ot < 4; ++ot) {
            f32x4 c = {0.f, 0.f, 0.f, 0.f};
            if (hasKs0) {
                short8 a = *(const short8*)&s_x1T[(16 * ot + l15) * X1TS + 8 * q];
                c = MFMA16(a, adjB0, c);
            }
            if (hasKs1) {
                short8 a = *(const short8*)&s_x1T[(16 * ot + l15) * X1TS + 8 * q + 32];
                c = MFMA16(a, adjB1, c);
            }
            // C: col i = 16w+l15 (lane), rows o = 16ot+4q+reg -> b64 write
            short4v nv;
            nv[0] = f2bf(c[0]); nv[1] = f2bf(c[1]);
            nv[2] = f2bf(c[2]); nv[3] = f2bf(c[3]);
            *(short4v*)&cat[(16 * w + l15) * CAS + 64 + 16 * ot + 4 * q] = nv;
        }
        __syncthreads();   // barrier 2: n1 consumed cross-wave; also fences
                           // s_x1T reuse by next iteration's phase 1

        // ---- MFMA#2: wave w owns o-tile nt=w; loop all 4 i-tiles ----
        {
            f32x4 z = {0.f, 0.f, 0.f, 0.f};
            f32x4 acc2[4] = {z, z, z, z};
            #pragma unroll
            for (int it2 = 0; it2 < 4; ++it2) {
                short8 a2[4];
                #pragma unroll
                for (int ks = 0; ks < 4; ++ks)
                    a2[ks] = *(const short8*)&cat[(16 * it2 + l15) * CAS + 32 * ks + 8 * q];
                #pragma unroll
                for (int ks = 0; ks < 4; ++ks) {
                    acc2[it2] = MFMA16(a2[ks], whf[ks], acc2[it2]);
                    acc2[it2] = MFMA16(a2[ks], wlf[ks], acc2[it2]);
                }
            }
            float total = 0.f;
            #pragma unroll
            for (int it2 = 0; it2 < 4; ++it2) {
                float s = fmaxf(acc2[it2][0] + bo, 0.f) + fmaxf(acc2[it2][1] + bo, 0.f)
                        + fmaxf(acc2[it2][2] + bo, 0.f) + fmaxf(acc2[it2][3] + bo, 0.f);
                s += __shfl_xor(s, 16);
                s += __shfl_xor(s, 32);
                total += s;           // ((s0+s1)+s2)+s3 — same order as before
            }
            if (l < 16)
                feats[(size_t)m * 64 + 16 * w + l15] = total;
        }
        // no trailing barrier: next iter writes cat buffer pb^1; x1T writes are
        // fenced by barrier 2 above (all x1T reads complete before it).
        m += SGRID;
        p += SSTEP_P; b += SSTEP_B;
        if (p >= PNUM) { p -= PNUM; ++b; }
        pb ^= 1;
    }
}

// ---------------------------------------------------------------------------
// GEMM: C[M x 512] = A[M x K] @ BT[K x 512] + bias1 + bias2  (verified)
// ---------------------------------------------------------------------------
template <int K>
__launch_bounds__(256, 2)
__global__ void gemm512_kernel(const float* __restrict__ A, const float* __restrict__ BT,
                               const float* __restrict__ bias1, const float* __restrict__ bias2,
                               float* __restrict__ C) {
    constexpr int K4 = K / 4;
    __shared__ __align__(16) float s_a[64 * K];
    const int tid = threadIdx.x;
    const int m0 = blockIdx.x * 64;
    const int j0 = blockIdx.y * 128;

    const float4* Ag = (const float4*)A;
    for (int e = tid; e < 16 * K; e += 256) {
        int row = e / K4, c = e % K4;
        ((float4*)s_a)[row * K4 + (c ^ ((row >> 2) & 7))] = Ag[(size_t)(m0 + row) * K4 + c];
    }
    __syncthreads();

    const int ti = tid >> 4, tj = tid & 15;
    const int swz = ti & 7;
    const int j = j0 + tj * 8;
    const int jb = (j0 >> 2) + tj * 2;
    const float4* BT4 = (const float4*)BT;

    float4 accL[4], accH[4];
    #pragma unroll
    for (int ii = 0; ii < 4; ++ii) {
        accL[ii] = make_float4(0.f, 0.f, 0.f, 0.f);
        accH[ii] = make_float4(0.f, 0.f, 0.f, 0.f);
    }
    for (int c = 0; c < K4; ++c) {
        float4 a4[4];
        #pragma unroll
        for (int ii = 0; ii < 4; ++ii)
            a4[ii] = ((const float4*)s_a)[(4 * ti + ii) * K4 + (c ^ swz)];
        #pragma unroll
        for (int kk = 0; kk < 4; ++kk) {
            float4 b1 = BT4[(size_t)(c * 4 + kk) * 128 + jb];
            float4 b2 = BT4[(size_t)(c * 4 + kk) * 128 + jb + 1];
            #pragma unroll
            for (int ii = 0; ii < 4; ++ii) {
                float av = f4c(a4[ii], kk);
                fma4(accL[ii], av, b1);
                fma4(accH[ii], av, b2);
            }
        }
    }
    float4 bL = make_float4(bias1[j] + bias2[j], bias1[j + 1] + bias2[j + 1],
                            bias1[j + 2] + bias2[j + 2], bias1[j + 3] + bias2[j + 3]);
    float4 bH = make_float4(bias1[j + 4] + bias2[j + 4], bias1[j + 5] + bias2[j + 5],
                            bias1[j + 6] + bias2[j + 6], bias1[j + 7] + bias2[j + 7]);
    #pragma unroll
    for (int ii = 0; ii < 4; ++ii) {
        size_t row = (size_t)(m0 + 4 * ti + ii);
        float4 oL = make_float4(accL[ii].x + bL.x, accL[ii].y + bL.y,
                                accL[ii].z + bL.z, accL[ii].w + bL.w);
        float4 oH = make_float4(accH[ii].x + bH.x, accH[ii].y + bH.y,
                                accH[ii].z + bH.z, accH[ii].w + bH.w);
        ((float4*)C)[(row * 512 + j) >> 2] = oL;
        ((float4*)C)[(row * 512 + j + 4) >> 2] = oH;
    }
}

// ---------------------------------------------------------------------------
// LSTM recurrence v4: MFMA (unchanged from R14/R15).
// ---------------------------------------------------------------------------
#define HS 136    // s_h row stride in shorts (68 dwords = 4 mod 32)
#define GS 516    // s_g2 row stride in floats (516 = 4 mod 32, 16B-mult)

template <bool FINAL>
__launch_bounds__(512)
__global__ void lstm_mfma(const float* __restrict__ xg, const short* __restrict__ whhfG,
                          float* __restrict__ out0,
                          const float* __restrict__ Wc1, const float* __restrict__ bc1,
                          const float* __restrict__ Wc2, const float* __restrict__ bc2,
                          float* __restrict__ out) {
    __shared__ __align__(16) short s_h[16 * HS];    // h bf16 [m][k]
    __shared__ __align__(16) float s_g2[16 * GS];   // mfma gates fp32 [m][n]
    __shared__ __align__(16) float s_hid[16 * 68];
    const int tid = threadIdx.x;
    const int w = tid >> 6, l = tid & 63, quad = l >> 4, l15 = l & 15;
    const int b0 = blockIdx.x * 16;
    const int u = tid & 127, r0 = tid >> 7;

    short8 whf[16], wlf[16];
    #pragma unroll
    for (int nt = 0; nt < 4; ++nt)
        #pragma unroll
        for (int ks = 0; ks < 4; ++ks) {
            size_t NT = (size_t)(w * 4 + nt);
            whf[nt * 4 + ks] = *(const short8*)(whhfG + (((NT * 4 + ks) * 2 + 0) * 64 + l) * 8);
            wlf[nt * 4 + ks] = *(const short8*)(whhfG + (((NT * 4 + ks) * 2 + 1) * 64 + l) * 8);
        }

    float c[4] = {0.f, 0.f, 0.f, 0.f};
    for (int e = tid; e < 16 * HS; e += 512) s_h[e] = 0;
    __syncthreads();

    for (int t = 0; t < 31; ++t) {
        float xgv[16];
        #pragma unroll
        for (int j = 0; j < 4; ++j) {
            size_t base = ((size_t)(b0 + r0 * 4 + j) * PNUM + t) * 512 + u;
            xgv[j * 4 + 0] = xg[base];
            xgv[j * 4 + 1] = xg[base + 128];
            xgv[j * 4 + 2] = xg[base + 256];
            xgv[j * 4 + 3] = xg[base + 384];
        }

        short8 af[4];
        #pragma unroll
        for (int ks = 0; ks < 4; ++ks)
            af[ks] = *(const short8*)&s_h[l15 * HS + ks * 32 + quad * 8];
        f32x4 z = {0.f, 0.f, 0.f, 0.f};
        f32x4 acc[4] = {z, z, z, z};
        #pragma unroll
        for (int nt = 0; nt < 4; ++nt)
            #pragma unroll
            for (int ks = 0; ks < 4; ++ks) {
                acc[nt] = MFMA16(af[ks], whf[nt * 4 + ks], acc[nt]);
                acc[nt] = MFMA16(af[ks], wlf[nt * 4 + ks], acc[nt]);
            }
        #pragma unroll
        for (int nt = 0; nt < 4; ++nt) {
            int n = w * 64 + nt * 16 + l15;
            #pragma unroll
            for (int reg = 0; reg < 4; ++reg)
                s_g2[(quad * 4 + reg) * GS + n] = acc[nt][reg];
        }
        __syncthreads();

        #pragma unroll
        for (int j = 0; j < 4; ++j) {
            int rr = r0 * 4 + j;
            float gi = xgv[j * 4 + 0] + s_g2[rr * GS + u];
            float gf = xgv[j * 4 + 1] + s_g2[rr * GS + 128 + u];
            float gg = xgv[j * 4 + 2] + s_g2[rr * GS + 256 + u];
            float go = xgv[j * 4 + 3] + s_g2[rr * GS + 384 + u];
            float cn = sigf(gf) * c[j] + sigf(gi) * tanhfast(gg);
            float h = sigf(go) * tanhfast(cn);
            c[j] = cn;
            s_h[rr * HS + u] = f2bf(h);
            if (!FINAL)
                out0[((size_t)(b0 + rr) * PNUM + t) * 128 + u] = h;
        }
        __syncthreads();
    }

    if (FINAL) {
        #pragma unroll
        for (int it2 = 0; it2 < 2; ++it2) {
            int item = tid + it2 * 512;
            int rr = item >> 6, uu = item & 63;
            float acc = bc1[uu];
            const float* wv = Wc1 + (size_t)uu * 128;
            #pragma unroll 8
            for (int k = 0; k < 128; ++k) acc += wv[k] * bf2f(s_h[rr * HS + k]);
            s_hid[rr * 68 + uu] = fmaxf(acc, 0.f);
        }
        __syncthreads();
        if (tid < 176) {
            int rr = tid / 11, cc = tid % 11;
            float acc = bc2[cc];
            #pragma unroll
            for (int uu = 0; uu < 64; ++uu) acc += Wc2[cc * 64 + uu] * s_hid[rr * 68 + uu];
            out[(size_t)(b0 + rr) * 11 + cc] = acc;
        }
    }
}

// ---------------------------------------------------------------------------
extern "C" void kernel_launch(void* const* d_in, const int* in_sizes, int n_in,
                              void* d_out, int out_size, void* d_ws, size_t ws_size,
                              hipStream_t stream) {
    (void)in_sizes; (void)n_in; (void)out_size; (void)ws_size;
    const float* I    = (const float*)d_in[0];
    const float* Q    = (const float*)d_in[1];
    const float* ew   = (const float*)d_in[2];
    const float* Wn1  = (const float*)d_in[3];
    const float* bn1  = (const float*)d_in[4];
    const float* Ws1  = (const float*)d_in[5];
    const float* bs1  = (const float*)d_in[6];
    const float* Wn2  = (const float*)d_in[7];
    const float* bn2  = (const float*)d_in[8];
    const float* Ws2  = (const float*)d_in[9];
    const float* bs2  = (const float*)d_in[10];
    const float* Wih0 = (const float*)d_in[11];
    const float* Whh0 = (const float*)d_in[12];
    const float* bih0 = (const float*)d_in[13];
    const float* bhh0 = (const float*)d_in[14];
    const float* Wih1 = (const float*)d_in[15];
    const float* Whh1 = (const float*)d_in[16];
    const float* bih1 = (const float*)d_in[17];
    const float* bhh1 = (const float*)d_in[18];
    const float* Wc1  = (const float*)d_in[19];
    const float* bc1  = (const float*)d_in[20];
    const float* Wc2  = (const float*)d_in[21];
    const float* bc2  = (const float*)d_in[22];
    float* out = (float*)d_out;

    // workspace (floats): ~90.4 MB
    float* wsp   = (float*)d_ws;
    float* adjn  = wsp;                           // 4096
    float* WihT0 = adjn  + 4096;                  // 32768
    float* WihT1 = WihT0 + 32768;                 // 65536
    short* adjfG  = (short*)(WihT1 + 65536);      // 3072 shorts
    short* wcatfG = adjfG + 3072;                 // 16384 shorts
    short* whhf0G = wcatfG + 16384;               // 131072 shorts
    short* whhf1G = whhf0G + 131072;              // 131072 shorts  (=> 140800 floats total)
    float* feats = WihT1 + 65536 + 140800;        // 2031616
    float* out0  = feats + 2031616;               // 4063232
    float* xg    = out0  + 4063232;               // 16252928 (shared by both layers)

    adj_kernel<<<1, 64, 0, stream>>>(ew, adjn);
    prep_kernel<<<522, 256, 0, stream>>>(Wih0, Whh0, Wih1, Whh1, adjn, Ws2, Wn2,
                                         WihT0, WihT1, adjfG, wcatfG, whhf0G, whhf1G);
    sage_mfma<<<SGRID, 256, 0, stream>>>(I, Q, adjn, Wn1, bn1, Ws1, bs1,
                                         bn2, bs2, adjfG, wcatfG, feats);
    gemm512_kernel<64><<<dim3(496, 4), 256, 0, stream>>>(feats, WihT0, bih0, bhh0, xg);
    lstm_mfma<false><<<64, 512, 0, stream>>>(xg, whhf0G, out0,
                                             nullptr, nullptr, nullptr, nullptr, nullptr);
    gemm512_kernel<128><<<dim3(496, 4), 256, 0, stream>>>(out0, WihT1, bih1, bhh1, xg);
    lstm_mfma<true><<<64, 512, 0, stream>>>(xg, whhf1G, nullptr,
                                            Wc1, bc1, Wc2, bc2, out);
}

// Round 8
// 568.008 us; speedup vs baseline: 1.0315x; 1.0315x over previous
//
#include <hip/hip_runtime.h>
#include <hip/hip_bf16.h>
#include <math.h>

#define L_SZ 1024
#define STRIDE_ 32
#define WIN 8
#define PNUM 31
#define NPATCH 31744   // 1024 batches x 31 patches
#define SGRID 512      // 256 CU x 2 blocks/CU co-resident (R22 evidence: (256,2)
                       // pins 2 blocks/CU; 768-grid ran a half-idle 256-block tail)

// LDS row strides (in shorts). dword strides = 36/68 = 4 mod 32 -> 2-way banks (free).
#define X1TS 72
#define CAS  136

typedef __attribute__((ext_vector_type(8))) short short8;
typedef __attribute__((ext_vector_type(4))) short short4v;
typedef __attribute__((ext_vector_type(4))) float f32x4;

#define MFMA16(a, b, c) __builtin_amdgcn_mfma_f32_16x16x32_bf16(a, b, c, 0, 0, 0)

__device__ __forceinline__ float sigf(float x) { return 1.0f / (1.0f + __expf(-x)); }
__device__ __forceinline__ float tanhfast(float x) {
    float ax = fabsf(x);
    float t = __expf(-2.0f * ax);
    return copysignf((1.0f - t) / (1.0f + t), x);
}
__device__ __forceinline__ short f2bf(float f) {
    __hip_bfloat16 h = __float2bfloat16(f);   // RNE
    return *reinterpret_cast<short*>(&h);
}
__device__ __forceinline__ float bf2f(short s) {
    __hip_bfloat16 h = *reinterpret_cast<__hip_bfloat16*>(&s);
    return __bfloat162float(h);
}
__device__ __forceinline__ float f4c(float4 v, int k) {
    return k == 0 ? v.x : (k == 1 ? v.y : (k == 2 ? v.z : v.w));
}
__device__ __forceinline__ void fma4(float4& acc, float s, float4 v) {
    acc.x += s * v.x; acc.y += s * v.y; acc.z += s * v.z; acc.w += s * v.w;
}

// ---------------------------------------------------------------------------
// adjn[i][j] = sigmoid(ew[i][j]) * mask(|i-j|<=8, i!=j) * deg_inv[i]
// ---------------------------------------------------------------------------
__global__ void adj_kernel(const float* __restrict__ ew, float* __restrict__ adjn) {
    int i = threadIdx.x;
    if (i >= 64) return;
    float sum = 0.f;
    for (int j = 0; j < 64; ++j) {
        int d = i - j; d = d < 0 ? -d : d;
        float a = (d <= WIN && d != 0) ? sigf(ew[i * 64 + j]) : 0.f;
        sum += a;
    }
    float dinv = (sum > 0.f) ? 1.0f / sum : 0.f;
    for (int j = 0; j < 64; ++j) {
        int d = i - j; d = d < 0 ? -d : d;
        float a = (d <= WIN && d != 0) ? sigf(ew[i * 64 + j]) : 0.f;
        adjn[i * 64 + j] = a * dinv;
    }
}

// ---------------------------------------------------------------------------
// prep (unchanged from R15):
//   blocks   0..127 : Wih0T | 128..383 : Wih1T | 384..393 : sage frags
//   blocks 394..457 : Whh0 frags hi/lo | 458..521 : Whh1 frags hi/lo
// ---------------------------------------------------------------------------
__global__ void prep_kernel(const float* __restrict__ Wih0, const float* __restrict__ Whh0,
                            const float* __restrict__ Wih1, const float* __restrict__ Whh1,
                            const float* __restrict__ adjn,
                            const float* __restrict__ Ws2, const float* __restrict__ Wn2,
                            float* __restrict__ Wih0T, float* __restrict__ Wih1T,
                            short* __restrict__ adjfG, short* __restrict__ wcatfG,
                            short* __restrict__ whhf0G, short* __restrict__ whhf1G) {
    int bid = blockIdx.x, tid = threadIdx.x;
    if (bid < 128) {
        int e = bid * 256 + tid;
        int k = e >> 9, j = e & 511;
        Wih0T[e] = Wih0[j * 64 + k];
        return;
    }
    if (bid < 384) {
        int e = (bid - 128) * 256 + tid;
        int k = e >> 9, j = e & 511;
        Wih1T[e] = Wih1[j * 128 + k];
        return;
    }
    if (bid < 394) {
        int t = (bid - 384) * 256 + tid;
        if (t >= 2432) return;
        int f = t >> 6, l = t & 63;
        int q = l >> 4, l15 = l & 15;
        short8 v;
        if (f < 6) {
            const int ntT[6] = {0, 1, 1, 2, 2, 3};
            const int ksT[6] = {0, 0, 1, 0, 1, 1};
            int row = l15 + 16 * ntT[f], col = 8 * q + 32 * ksT[f];
            #pragma unroll
            for (int e = 0; e < 8; ++e)
                v[e] = f2bf(adjn[row * 64 + col + e]);
            *(short8*)(adjfG + ((size_t)f * 64 + l) * 8) = v;
        } else {
            int fi = f - 6;
            int isLo = fi >= 16;
            int ff = isLo ? fi - 16 : fi;
            int nt = ff >> 2, ks = ff & 3;
            int oo = l15 + 16 * nt;
            #pragma unroll
            for (int e = 0; e < 8; ++e) {
                int k = 32 * ks + 8 * q + e;
                float src = (k < 64) ? Ws2[oo * 64 + k] : Wn2[oo * 64 + (k - 64)];
                short hi = f2bf(src);
                v[e] = isLo ? f2bf(src - bf2f(hi)) : hi;
            }
            *(short8*)(wcatfG + ((size_t)fi * 64 + l) * 8) = v;
        }
        return;
    }
    {
        int layer = (bid < 458) ? 0 : 1;
        int base = layer ? 458 : 394;
        const float* Whh = layer ? Whh1 : Whh0;
        short* dst = layer ? whhf1G : whhf0G;
        int t = (bid - base) * 256 + tid;    // 0..16383
        int frag = t >> 6, l = t & 63;
        int hl = frag & 1, ks = (frag >> 1) & 3, NT = frag >> 3;
        int g = NT * 16 + (l & 15);
        int kbase = ks * 32 + (l >> 4) * 8;
        short8 v;
        #pragma unroll
        for (int e = 0; e < 8; ++e) {
            float src = Whh[(size_t)g * 128 + kbase + e];
            short hi = f2bf(src);
            v[e] = hl ? f2bf(src - bf2f(hi)) : hi;
        }
        *(short8*)(dst + (size_t)t * 8) = v;
    }
}

// ---------------------------------------------------------------------------
// Persistent fused SAGE, bf16 MFMA.
// R23: tail-free grid at the (256,2)-pinned residency. Evidence chain:
//  - (256,2) => compiler allocates for exactly 2 blocks/CU (R22: VGPR grew
//    to fill the license; occupancy immovable). (256,3/4) => spill (R17/R19).
//  - 768-grid at 2 blocks/CU = 512-block cohort + half-idle 256-block tail
//    (occ 18.6% time-avg). Per-iter time from R21: 197us / 82.7 iter-slots
//    = 2.38us (R19 phase1 restructure DID work; tail ate it).
//  - Fix: SGRID=512 (= 2 x 256 CU, exactly co-resident, zero tail);
//    62 iters/block => ~148us predicted.
// Body = R21 (fastest per-iter: VGPR 116): shuffle n0 + areg band + x0 reg
// prefetch + single x1T / double cat LDS (44,032 B), 2 barriers/iter.
// Bit-identical math & term order throughout.
// ---------------------------------------------------------------------------
__launch_bounds__(256, 2)
__global__ void sage_mfma(const float* __restrict__ I, const float* __restrict__ Q,
                          const float* __restrict__ adjn,
                          const float* __restrict__ Wn1, const float* __restrict__ bn1,
                          const float* __restrict__ Ws1, const float* __restrict__ bs1,
                          const float* __restrict__ bn2, const float* __restrict__ bs2,
                          const short* __restrict__ adjfG, const short* __restrict__ wcatfG,
                          float* __restrict__ feats) {
    __shared__ __align__(16) short s_x1T[64 * X1TS];     // x1^T [o][i] bf16 (single)
    __shared__ __align__(16) short s_cat[2][64 * CAS];   // [i][x1|n1] bf16 (double)

    const int tid = threadIdx.x;
    const int w = tid >> 6, l = tid & 63, q = l >> 4, l15 = l & 15;

    // adj frags for THIS wave's i-tile (band): w0:{ks0}, w1/w2:{ks0,ks1}, w3:{ks1}
    const bool hasKs0 = (w <= 2);
    const bool hasKs1 = (w >= 1);
    const int idx0 = (w == 0) ? 0 : (w == 1 ? 1 : 3);    // frag idx for (nt=w, ks=0)
    const int idx1 = (w == 1) ? 2 : (w == 2 ? 4 : 5);    // frag idx for (nt=w, ks=1)
    short8 adjB0 = {}, adjB1 = {};
    if (hasKs0) adjB0 = *(const short8*)(adjfG + ((size_t)idx0 * 64 + l) * 8);
    if (hasKs1) adjB1 = *(const short8*)(adjfG + ((size_t)idx1 * 64 + l) * 8);

    // weight frags for THIS wave's o-tile (nt = w): 8 frags = 32 VGPRs
    short8 whf[4], wlf[4];
    #pragma unroll
    for (int ks = 0; ks < 4; ++ks) {
        whf[ks] = *(const short8*)(wcatfG + ((size_t)(w * 4 + ks) * 64 + l) * 8);
        wlf[ks] = *(const short8*)(wcatfG + ((size_t)(w * 4 + ks + 16) * 64 + l) * 8);
    }
    // bias for this wave's output channel (loop-invariant)
    const int oo = l15 + 16 * w;
    const float bo = bs2[oo] + bn2[oo];

    // adjn band in registers: lane l = row i; zeros outside [0,64)
    float areg[17];
    #pragma unroll
    for (int d = 0; d < 17; ++d) {
        int j = l + d - WIN;
        areg[d] = (j >= 0 && j < 64) ? adjn[l * 64 + j] : 0.f;
    }

    // initial x0 (lane l holds column i = l; same in all 4 waves, L1-broadcast)
    int m = blockIdx.x;
    float x0a, x0b;
    {
        int b = m / PNUM, p = m % PNUM;
        x0a = I[(size_t)b * L_SZ + p * STRIDE_ + l];
        x0b = Q[(size_t)b * L_SZ + p * STRIDE_ + l];
    }

    int pb = 0;
    while (m < NPATCH) {
        // prefetch next patch's x0 — independent, hides global latency
        const int mn = m + SGRID;
        float nxa = 0.f, nxb = 0.f;
        if (mn < NPATCH) {
            int bn = mn / PNUM, pn = mn % PNUM;
            nxa = I[(size_t)bn * L_SZ + pn * STRIDE_ + l];
            nxb = Q[(size_t)bn * L_SZ + pn * STRIDE_ + l];
        }

        short* __restrict__ cat = s_cat[pb];

        // ---- Phase 1: n0 via shuffles, x1 = relu(...) ----
        {
            // fixed-trip window; out-of-band areg == 0.0f exactly
            float n0a = 0.f, n0b = 0.f;
            #pragma unroll
            for (int d = 0; d < 17; ++d) {
                int j = l + d - WIN;
                float xa = __shfl(x0a, j, 64);
                float xb = __shfl(x0b, j, 64);
                n0a += areg[d] * xa;
                n0b += areg[d] * xb;
            }
            union { short s[16]; short8 v[2]; } pk;
            #pragma unroll
            for (int t = 0; t < 16; ++t) {
                int o = w * 16 + t;
                float2 wsv = ((const float2*)Ws1)[o];
                float2 wnv = ((const float2*)Wn1)[o];
                float v = bs1[o] + bn1[o] + wsv.x * x0a + wsv.y * x0b
                                          + wnv.x * n0a + wnv.y * n0b;
                v = fmaxf(v, 0.f);
                short bv = f2bf(v);
                s_x1T[o * X1TS + l] = bv;
                pk.s[t] = bv;
            }
            *(short8*)&cat[l * CAS + w * 16]     = pk.v[0];
            *(short8*)&cat[l * CAS + w * 16 + 8] = pk.v[1];
        }
        __syncthreads();   // barrier 1: x1T/cat(x1) visible to all waves

        // ---- MFMA#1: n1^T for i-tile w. A = x1T o-tiles, B = adj cols. ----
        #pragma unroll
        for (int ot = 0; ot < 4; ++ot) {
            f32x4 c = {0.f, 0.f, 0.f, 0.f};
            if (hasKs0) {
                short8 a = *(const short8*)&s_x1T[(16 * ot + l15) * X1TS + 8 * q];
                c = MFMA16(a, adjB0, c);
            }
            if (hasKs1) {
                short8 a = *(const short8*)&s_x1T[(16 * ot + l15) * X1TS + 8 * q + 32];
                c = MFMA16(a, adjB1, c);
            }
            // C: col i = 16w+l15 (lane), rows o = 16ot+4q+reg -> b64 write
            short4v nv;
            nv[0] = f2bf(c[0]); nv[1] = f2bf(c[1]);
            nv[2] = f2bf(c[2]); nv[3] = f2bf(c[3]);
            *(short4v*)&cat[(16 * w + l15) * CAS + 64 + 16 * ot + 4 * q] = nv;
        }
        __syncthreads();   // barrier 2: n1 consumed cross-wave; also fences
                           // s_x1T reuse by next iteration's phase 1

        // ---- MFMA#2: wave w owns o-tile nt=w; loop all 4 i-tiles ----
        {
            f32x4 z = {0.f, 0.f, 0.f, 0.f};
            f32x4 acc2[4] = {z, z, z, z};
            #pragma unroll
            for (int it2 = 0; it2 < 4; ++it2) {
                short8 a2[4];
                #pragma unroll
                for (int ks = 0; ks < 4; ++ks)
                    a2[ks] = *(const short8*)&cat[(16 * it2 + l15) * CAS + 32 * ks + 8 * q];
                #pragma unroll
                for (int ks = 0; ks < 4; ++ks) {
                    acc2[it2] = MFMA16(a2[ks], whf[ks], acc2[it2]);
                    acc2[it2] = MFMA16(a2[ks], wlf[ks], acc2[it2]);
                }
            }
            float total = 0.f;
            #pragma unroll
            for (int it2 = 0; it2 < 4; ++it2) {
                float s = fmaxf(acc2[it2][0] + bo, 0.f) + fmaxf(acc2[it2][1] + bo, 0.f)
                        + fmaxf(acc2[it2][2] + bo, 0.f) + fmaxf(acc2[it2][3] + bo, 0.f);
                s += __shfl_xor(s, 16);
                s += __shfl_xor(s, 32);
                total += s;           // ((s0+s1)+s2)+s3 — same order as before
            }
            if (l < 16)
                feats[(size_t)m * 64 + 16 * w + l15] = total;
        }
        // no trailing barrier: next iter writes cat buffer pb^1; x1T writes are
        // fenced by barrier 2 above (all x1T reads complete before it).
        x0a = nxa; x0b = nxb; m = mn; pb ^= 1;
    }
}

// ---------------------------------------------------------------------------
// GEMM: C[M x 512] = A[M x K] @ BT[K x 512] + bias1 + bias2  (verified)
// ---------------------------------------------------------------------------
template <int K>
__launch_bounds__(256, 2)
__global__ void gemm512_kernel(const float* __restrict__ A, const float* __restrict__ BT,
                               const float* __restrict__ bias1, const float* __restrict__ bias2,
                               float* __restrict__ C) {
    constexpr int K4 = K / 4;
    __shared__ __align__(16) float s_a[64 * K];
    const int tid = threadIdx.x;
    const int m0 = blockIdx.x * 64;
    const int j0 = blockIdx.y * 128;

    const float4* Ag = (const float4*)A;
    for (int e = tid; e < 16 * K; e += 256) {
        int row = e / K4, c = e % K4;
        ((float4*)s_a)[row * K4 + (c ^ ((row >> 2) & 7))] = Ag[(size_t)(m0 + row) * K4 + c];
    }
    __syncthreads();

    const int ti = tid >> 4, tj = tid & 15;
    const int swz = ti & 7;
    const int j = j0 + tj * 8;
    const int jb = (j0 >> 2) + tj * 2;
    const float4* BT4 = (const float4*)BT;

    float4 accL[4], accH[4];
    #pragma unroll
    for (int ii = 0; ii < 4; ++ii) {
        accL[ii] = make_float4(0.f, 0.f, 0.f, 0.f);
        accH[ii] = make_float4(0.f, 0.f, 0.f, 0.f);
    }
    for (int c = 0; c < K4; ++c) {
        float4 a4[4];
        #pragma unroll
        for (int ii = 0; ii < 4; ++ii)
            a4[ii] = ((const float4*)s_a)[(4 * ti + ii) * K4 + (c ^ swz)];
        #pragma unroll
        for (int kk = 0; kk < 4; ++kk) {
            float4 b1 = BT4[(size_t)(c * 4 + kk) * 128 + jb];
            float4 b2 = BT4[(size_t)(c * 4 + kk) * 128 + jb + 1];
            #pragma unroll
            for (int ii = 0; ii < 4; ++ii) {
                float av = f4c(a4[ii], kk);
                fma4(accL[ii], av, b1);
                fma4(accH[ii], av, b2);
            }
        }
    }
    float4 bL = make_float4(bias1[j] + bias2[j], bias1[j + 1] + bias2[j + 1],
                            bias1[j + 2] + bias2[j + 2], bias1[j + 3] + bias2[j + 3]);
    float4 bH = make_float4(bias1[j + 4] + bias2[j + 4], bias1[j + 5] + bias2[j + 5],
                            bias1[j + 6] + bias2[j + 6], bias1[j + 7] + bias2[j + 7]);
    #pragma unroll
    for (int ii = 0; ii < 4; ++ii) {
        size_t row = (size_t)(m0 + 4 * ti + ii);
        float4 oL = make_float4(accL[ii].x + bL.x, accL[ii].y + bL.y,
                                accL[ii].z + bL.z, accL[ii].w + bL.w);
        float4 oH = make_float4(accH[ii].x + bH.x, accH[ii].y + bH.y,
                                accH[ii].z + bH.z, accH[ii].w + bH.w);
        ((float4*)C)[(row * 512 + j) >> 2] = oL;
        ((float4*)C)[(row * 512 + j + 4) >> 2] = oH;
    }
}

// ---------------------------------------------------------------------------
// LSTM recurrence v4: MFMA (unchanged from R14/R15).
// ---------------------------------------------------------------------------
#define HS 136    // s_h row stride in shorts (68 dwords = 4 mod 32)
#define GS 516    // s_g2 row stride in floats (516 = 4 mod 32, 16B-mult)

template <bool FINAL>
__launch_bounds__(512)
__global__ void lstm_mfma(const float* __restrict__ xg, const short* __restrict__ whhfG,
                          float* __restrict__ out0,
                          const float* __restrict__ Wc1, const float* __restrict__ bc1,
                          const float* __restrict__ Wc2, const float* __restrict__ bc2,
                          float* __restrict__ out) {
    __shared__ __align__(16) short s_h[16 * HS];    // h bf16 [m][k]
    __shared__ __align__(16) float s_g2[16 * GS];   // mfma gates fp32 [m][n]
    __shared__ __align__(16) float s_hid[16 * 68];
    const int tid = threadIdx.x;
    const int w = tid >> 6, l = tid & 63, quad = l >> 4, l15 = l & 15;
    const int b0 = blockIdx.x * 16;
    const int u = tid & 127, r0 = tid >> 7;

    short8 whf[16], wlf[16];
    #pragma unroll
    for (int nt = 0; nt < 4; ++nt)
        #pragma unroll
        for (int ks = 0; ks < 4; ++ks) {
            size_t NT = (size_t)(w * 4 + nt);
            whf[nt * 4 + ks] = *(const short8*)(whhfG + (((NT * 4 + ks) * 2 + 0) * 64 + l) * 8);
            wlf[nt * 4 + ks] = *(const short8*)(whhfG + (((NT * 4 + ks) * 2 + 1) * 64 + l) * 8);
        }

    float c[4] = {0.f, 0.f, 0.f, 0.f};
    for (int e = tid; e < 16 * HS; e += 512) s_h[e] = 0;
    __syncthreads();

    for (int t = 0; t < 31; ++t) {
        float xgv[16];
        #pragma unroll
        for (int j = 0; j < 4; ++j) {
            size_t base = ((size_t)(b0 + r0 * 4 + j) * PNUM + t) * 512 + u;
            xgv[j * 4 + 0] = xg[base];
            xgv[j * 4 + 1] = xg[base + 128];
            xgv[j * 4 + 2] = xg[base + 256];
            xgv[j * 4 + 3] = xg[base + 384];
        }

        short8 af[4];
        #pragma unroll
        for (int ks = 0; ks < 4; ++ks)
            af[ks] = *(const short8*)&s_h[l15 * HS + ks * 32 + quad * 8];
        f32x4 z = {0.f, 0.f, 0.f, 0.f};
        f32x4 acc[4] = {z, z, z, z};
        #pragma unroll
        for (int nt = 0; nt < 4; ++nt)
            #pragma unroll
            for (int ks = 0; ks < 4; ++ks) {
                acc[nt] = MFMA16(af[ks], whf[nt * 4 + ks], acc[nt]);
                acc[nt] = MFMA16(af[ks], wlf[nt * 4 + ks], acc[nt]);
            }
        #pragma unroll
        for (int nt = 0; nt < 4; ++nt) {
            int n = w * 64 + nt * 16 + l15;
            #pragma unroll
            for (int reg = 0; reg < 4; ++reg)
                s_g2[(quad * 4 + reg) * GS + n] = acc[nt][reg];
        }
        __syncthreads();

        #pragma unroll
        for (int j = 0; j < 4; ++j) {
            int rr = r0 * 4 + j;
            float gi = xgv[j * 4 + 0] + s_g2[rr * GS + u];
            float gf = xgv[j * 4 + 1] + s_g2[rr * GS + 128 + u];
            float gg = xgv[j * 4 + 2] + s_g2[rr * GS + 256 + u];
            float go = xgv[j * 4 + 3] + s_g2[rr * GS + 384 + u];
            float cn = sigf(gf) * c[j] + sigf(gi) * tanhfast(gg);
            float h = sigf(go) * tanhfast(cn);
            c[j] = cn;
            s_h[rr * HS + u] = f2bf(h);
            if (!FINAL)
                out0[((size_t)(b0 + rr) * PNUM + t) * 128 + u] = h;
        }
        __syncthreads();
    }

    if (FINAL) {
        #pragma unroll
        for (int it2 = 0; it2 < 2; ++it2) {
            int item = tid + it2 * 512;
            int rr = item >> 6, uu = item & 63;
            float acc = bc1[uu];
            const float* wv = Wc1 + (size_t)uu * 128;
            #pragma unroll 8
            for (int k = 0; k < 128; ++k) acc += wv[k] * bf2f(s_h[rr * HS + k]);
            s_hid[rr * 68 + uu] = fmaxf(acc, 0.f);
        }
        __syncthreads();
        if (tid < 176) {
            int rr = tid / 11, cc = tid % 11;
            float acc = bc2[cc];
            #pragma unroll
            for (int uu = 0; uu < 64; ++uu) acc += Wc2[cc * 64 + uu] * s_hid[rr * 68 + uu];
            out[(size_t)(b0 + rr) * 11 + cc] = acc;
        }
    }
}

// ---------------------------------------------------------------------------
extern "C" void kernel_launch(void* const* d_in, const int* in_sizes, int n_in,
                              void* d_out, int out_size, void* d_ws, size_t ws_size,
                              hipStream_t stream) {
    (void)in_sizes; (void)n_in; (void)out_size; (void)ws_size;
    const float* I    = (const float*)d_in[0];
    const float* Q    = (const float*)d_in[1];
    const float* ew   = (const float*)d_in[2];
    const float* Wn1  = (const float*)d_in[3];
    const float* bn1  = (const float*)d_in[4];
    const float* Ws1  = (const float*)d_in[5];
    const float* bs1  = (const float*)d_in[6];
    const float* Wn2  = (const float*)d_in[7];
    const float* bn2  = (const float*)d_in[8];
    const float* Ws2  = (const float*)d_in[9];
    const float* bs2  = (const float*)d_in[10];
    const float* Wih0 = (const float*)d_in[11];
    const float* Whh0 = (const float*)d_in[12];
    const float* bih0 = (const float*)d_in[13];
    const float* bhh0 = (const float*)d_in[14];
    const float* Wih1 = (const float*)d_in[15];
    const float* Whh1 = (const float*)d_in[16];
    const float* bih1 = (const float*)d_in[17];
    const float* bhh1 = (const float*)d_in[18];
    const float* Wc1  = (const float*)d_in[19];
    const float* bc1  = (const float*)d_in[20];
    const float* Wc2  = (const float*)d_in[21];
    const float* bc2  = (const float*)d_in[22];
    float* out = (float*)d_out;

    // workspace (floats): ~90.4 MB
    float* wsp   = (float*)d_ws;
    float* adjn  = wsp;                           // 4096
    float* WihT0 = adjn  + 4096;                  // 32768
    float* WihT1 = WihT0 + 32768;                 // 65536
    short* adjfG  = (short*)(WihT1 + 65536);      // 3072 shorts
    short* wcatfG = adjfG + 3072;                 // 16384 shorts
    short* whhf0G = wcatfG + 16384;               // 131072 shorts
    short* whhf1G = whhf0G + 131072;              // 131072 shorts  (=> 140800 floats total)
    float* feats = WihT1 + 65536 + 140800;        // 2031616
    float* out0  = feats + 2031616;               // 4063232
    float* xg    = out0  + 4063232;               // 16252928 (shared by both layers)

    adj_kernel<<<1, 64, 0, stream>>>(ew, adjn);
    prep_kernel<<<522, 256, 0, stream>>>(Wih0, Whh0, Wih1, Whh1, adjn, Ws2, Wn2,
                                         WihT0, WihT1, adjfG, wcatfG, whhf0G, whhf1G);
    sage_mfma<<<SGRID, 256, 0, stream>>>(I, Q, adjn, Wn1, bn1, Ws1, bs1,
                                         bn2, bs2, adjfG, wcatfG, feats);
    gemm512_kernel<64><<<dim3(496, 4), 256, 0, stream>>>(feats, WihT0, bih0, bhh0, xg);
    lstm_mfma<false><<<64, 512, 0, stream>>>(xg, whhf0G, out0,
                                             nullptr, nullptr, nullptr, nullptr, nullptr);
    gemm512_kernel<128><<<dim3(496, 4), 256, 0, stream>>>(out0, WihT1, bih1, bhh1, xg);
    lstm_mfma<true><<<64, 512, 0, stream>>>(xg, whhf1G, nullptr,
                                            Wc1, bc1, Wc2, bc2, out);
}

// Round 9
// 562.274 us; speedup vs baseline: 1.0420x; 1.0102x over previous
//
#include <hip/hip_runtime.h>
#include <hip/hip_bf16.h>
#include <math.h>

#define L_SZ 1024
#define STRIDE_ 32
#define WIN 8
#define PNUM 31
#define NPATCH 31744   // 1024 batches x 31 patches
#define SGRID 512      // 256 CU x 2 blocks/CU co-resident ((256,2)-pinned residency)

// LDS row strides (in shorts). dword strides = 36/68 = 4 mod 32 -> 2-way banks (free).
#define X1TS 72
#define CAS  136

typedef __attribute__((ext_vector_type(8))) short short8;
typedef __attribute__((ext_vector_type(4))) short short4v;
typedef __attribute__((ext_vector_type(4))) float f32x4;

#define MFMA16(a, b, c) __builtin_amdgcn_mfma_f32_16x16x32_bf16(a, b, c, 0, 0, 0)

__device__ __forceinline__ float sigf(float x) { return 1.0f / (1.0f + __expf(-x)); }
__device__ __forceinline__ float tanhfast(float x) {
    float ax = fabsf(x);
    float t = __expf(-2.0f * ax);
    return copysignf((1.0f - t) / (1.0f + t), x);
}
__device__ __forceinline__ short f2bf(float f) {
    __hip_bfloat16 h = __float2bfloat16(f);   // RNE
    return *reinterpret_cast<short*>(&h);
}
__device__ __forceinline__ float bf2f(short s) {
    __hip_bfloat16 h = *reinterpret_cast<__hip_bfloat16*>(&s);
    return __bfloat162float(h);
}
__device__ __forceinline__ float f4c(float4 v, int k) {
    return k == 0 ? v.x : (k == 1 ? v.y : (k == 2 ? v.z : v.w));
}
__device__ __forceinline__ void fma4(float4& acc, float s, float4 v) {
    acc.x += s * v.x; acc.y += s * v.y; acc.z += s * v.z; acc.w += s * v.w;
}

// ---------------------------------------------------------------------------
// adjn[i][j] = sigmoid(ew[i][j]) * mask(|i-j|<=8, i!=j) * deg_inv[i]
// ---------------------------------------------------------------------------
__global__ void adj_kernel(const float* __restrict__ ew, float* __restrict__ adjn) {
    int i = threadIdx.x;
    if (i >= 64) return;
    float sum = 0.f;
    for (int j = 0; j < 64; ++j) {
        int d = i - j; d = d < 0 ? -d : d;
        float a = (d <= WIN && d != 0) ? sigf(ew[i * 64 + j]) : 0.f;
        sum += a;
    }
    float dinv = (sum > 0.f) ? 1.0f / sum : 0.f;
    for (int j = 0; j < 64; ++j) {
        int d = i - j; d = d < 0 ? -d : d;
        float a = (d <= WIN && d != 0) ? sigf(ew[i * 64 + j]) : 0.f;
        adjn[i * 64 + j] = a * dinv;
    }
}

// ---------------------------------------------------------------------------
// prep (unchanged from R15):
//   blocks   0..127 : Wih0T | 128..383 : Wih1T | 384..393 : sage frags
//   blocks 394..457 : Whh0 frags hi/lo | 458..521 : Whh1 frags hi/lo
// ---------------------------------------------------------------------------
__global__ void prep_kernel(const float* __restrict__ Wih0, const float* __restrict__ Whh0,
                            const float* __restrict__ Wih1, const float* __restrict__ Whh1,
                            const float* __restrict__ adjn,
                            const float* __restrict__ Ws2, const float* __restrict__ Wn2,
                            float* __restrict__ Wih0T, float* __restrict__ Wih1T,
                            short* __restrict__ adjfG, short* __restrict__ wcatfG,
                            short* __restrict__ whhf0G, short* __restrict__ whhf1G) {
    int bid = blockIdx.x, tid = threadIdx.x;
    if (bid < 128) {
        int e = bid * 256 + tid;
        int k = e >> 9, j = e & 511;
        Wih0T[e] = Wih0[j * 64 + k];
        return;
    }
    if (bid < 384) {
        int e = (bid - 128) * 256 + tid;
        int k = e >> 9, j = e & 511;
        Wih1T[e] = Wih1[j * 128 + k];
        return;
    }
    if (bid < 394) {
        int t = (bid - 384) * 256 + tid;
        if (t >= 2432) return;
        int f = t >> 6, l = t & 63;
        int q = l >> 4, l15 = l & 15;
        short8 v;
        if (f < 6) {
            const int ntT[6] = {0, 1, 1, 2, 2, 3};
            const int ksT[6] = {0, 0, 1, 0, 1, 1};
            int row = l15 + 16 * ntT[f], col = 8 * q + 32 * ksT[f];
            #pragma unroll
            for (int e = 0; e < 8; ++e)
                v[e] = f2bf(adjn[row * 64 + col + e]);
            *(short8*)(adjfG + ((size_t)f * 64 + l) * 8) = v;
        } else {
            int fi = f - 6;
            int isLo = fi >= 16;
            int ff = isLo ? fi - 16 : fi;
            int nt = ff >> 2, ks = ff & 3;
            int oo = l15 + 16 * nt;
            #pragma unroll
            for (int e = 0; e < 8; ++e) {
                int k = 32 * ks + 8 * q + e;
                float src = (k < 64) ? Ws2[oo * 64 + k] : Wn2[oo * 64 + (k - 64)];
                short hi = f2bf(src);
                v[e] = isLo ? f2bf(src - bf2f(hi)) : hi;
            }
            *(short8*)(wcatfG + ((size_t)fi * 64 + l) * 8) = v;
        }
        return;
    }
    {
        int layer = (bid < 458) ? 0 : 1;
        int base = layer ? 458 : 394;
        const float* Whh = layer ? Whh1 : Whh0;
        short* dst = layer ? whhf1G : whhf0G;
        int t = (bid - base) * 256 + tid;    // 0..16383
        int frag = t >> 6, l = t & 63;
        int hl = frag & 1, ks = (frag >> 1) & 3, NT = frag >> 3;
        int g = NT * 16 + (l & 15);
        int kbase = ks * 32 + (l >> 4) * 8;
        short8 v;
        #pragma unroll
        for (int e = 0; e < 8; ++e) {
            float src = Whh[(size_t)g * 128 + kbase + e];
            short hi = f2bf(src);
            v[e] = hl ? f2bf(src - bf2f(hi)) : hi;
        }
        *(short8*)(dst + (size_t)t * 8) = v;
    }
}

// ---------------------------------------------------------------------------
// Persistent fused SAGE, bf16 MFMA.
// R24: patch-pair iteration to amortize the serial skeleton. R23 evidence:
// per-patch 1.53us at 2 blocks/CU, VALU 33 / MFMA 18 -> both pipes idle on
// dependent chains + 2 barrier-drains per patch. Bank conflicts (13.2M) are
// ~2-way aliasing everywhere = counter noise (m136: 2-way free), not a lever.
// Structure per iteration (31 iters, pair m0 = it*1024+bid, P1 = m0+512):
//   phase1(P0); phase1(P1)   <- independent, 2x ILP in the VALU-heaviest phase
//   [issue next-iter x0 loads -> hidden under MFMA phases]
//   barrier; MFMA#1(P0,P1); barrier; MFMA#2(P0 then P1, acc2 reused)
//   trailing barrier (protects x1T/cat reuse; no double-buffer)
// Barriers/patch 2.0 -> 1.5; MFMA#2 issues 64 back-to-back MFMAs.
// LDS: x1T[2] 18,432 + cat[2] 34,816 = 53,248 B x 2 blocks = 106.5 KB.
// Regs ~140 (acc2 sequential) under the (256,2) license that held 116-128
// without spill (R20-R23). Spill alarm: FETCH >> 8 MB.
// Per-patch math, layouts, and ((s0+s1)+s2)+s3 order unchanged -> bit-identical.
// ---------------------------------------------------------------------------
__launch_bounds__(256, 2)
__global__ void sage_mfma(const float* __restrict__ I, const float* __restrict__ Q,
                          const float* __restrict__ adjn,
                          const float* __restrict__ Wn1, const float* __restrict__ bn1,
                          const float* __restrict__ Ws1, const float* __restrict__ bs1,
                          const float* __restrict__ bn2, const float* __restrict__ bs2,
                          const short* __restrict__ adjfG, const short* __restrict__ wcatfG,
                          float* __restrict__ feats) {
    __shared__ __align__(16) short s_x1T[2][64 * X1TS];  // x1^T [o][i] bf16, per patch
    __shared__ __align__(16) short s_cat[2][64 * CAS];   // [i][x1|n1] bf16, per patch

    const int tid = threadIdx.x;
    const int w = tid >> 6, l = tid & 63, q = l >> 4, l15 = l & 15;

    // adj frags for THIS wave's i-tile (band): w0:{ks0}, w1/w2:{ks0,ks1}, w3:{ks1}
    const bool hasKs0 = (w <= 2);
    const bool hasKs1 = (w >= 1);
    const int idx0 = (w == 0) ? 0 : (w == 1 ? 1 : 3);    // frag idx for (nt=w, ks=0)
    const int idx1 = (w == 1) ? 2 : (w == 2 ? 4 : 5);    // frag idx for (nt=w, ks=1)
    short8 adjB0 = {}, adjB1 = {};
    if (hasKs0) adjB0 = *(const short8*)(adjfG + ((size_t)idx0 * 64 + l) * 8);
    if (hasKs1) adjB1 = *(const short8*)(adjfG + ((size_t)idx1 * 64 + l) * 8);

    // weight frags for THIS wave's o-tile (nt = w): 8 frags = 32 VGPRs
    short8 whf[4], wlf[4];
    #pragma unroll
    for (int ks = 0; ks < 4; ++ks) {
        whf[ks] = *(const short8*)(wcatfG + ((size_t)(w * 4 + ks) * 64 + l) * 8);
        wlf[ks] = *(const short8*)(wcatfG + ((size_t)(w * 4 + ks + 16) * 64 + l) * 8);
    }
    // bias for this wave's output channel (loop-invariant)
    const int oo = l15 + 16 * w;
    const float bo = bs2[oo] + bn2[oo];

    // adjn band in registers: lane l = row i; zeros outside [0,64)
    float areg[17];
    #pragma unroll
    for (int d = 0; d < 17; ++d) {
        int j = l + d - WIN;
        areg[d] = (j >= 0 && j < 64) ? adjn[l * 64 + j] : 0.f;
    }

    // preload iter-0 x0 for both patches (lane l holds column i = l)
    float x0a[2], x0b[2];
    #pragma unroll
    for (int P = 0; P < 2; ++P) {
        int m = blockIdx.x + P * 512;
        int b = m / PNUM, p = m % PNUM;
        x0a[P] = I[(size_t)b * L_SZ + p * STRIDE_ + l];
        x0b[P] = Q[(size_t)b * L_SZ + p * STRIDE_ + l];
    }

    for (int it = 0; it < 31; ++it) {
        const int m0 = it * 1024 + blockIdx.x;

        // ---- Phase 1 (both patches): n0 via shuffles, x1 = relu(...) ----
        #pragma unroll
        for (int P = 0; P < 2; ++P) {
            float n0a = 0.f, n0b = 0.f;
            #pragma unroll
            for (int d = 0; d < 17; ++d) {
                int j = l + d - WIN;
                float xa = __shfl(x0a[P], j, 64);
                float xb = __shfl(x0b[P], j, 64);
                n0a += areg[d] * xa;          // out-of-band areg == 0.0f exactly
                n0b += areg[d] * xb;
            }
            union { short s[16]; short8 v[2]; } pk;
            #pragma unroll
            for (int t = 0; t < 16; ++t) {
                int o = w * 16 + t;
                float2 wsv = ((const float2*)Ws1)[o];
                float2 wnv = ((const float2*)Wn1)[o];
                float v = bs1[o] + bn1[o] + wsv.x * x0a[P] + wsv.y * x0b[P]
                                          + wnv.x * n0a + wnv.y * n0b;
                v = fmaxf(v, 0.f);
                short bv = f2bf(v);
                s_x1T[P][o * X1TS + l] = bv;
                pk.s[t] = bv;
            }
            *(short8*)&s_cat[P][l * CAS + w * 16]     = pk.v[0];
            *(short8*)&s_cat[P][l * CAS + w * 16 + 8] = pk.v[1];
        }

        // issue next-iter x0 loads now (current values consumed) — latency
        // hides under the MFMA phases below
        if (it + 1 < 31) {
            #pragma unroll
            for (int P = 0; P < 2; ++P) {
                int m = (it + 1) * 1024 + blockIdx.x + P * 512;
                int b = m / PNUM, p = m % PNUM;
                x0a[P] = I[(size_t)b * L_SZ + p * STRIDE_ + l];
                x0b[P] = Q[(size_t)b * L_SZ + p * STRIDE_ + l];
            }
        }
        __syncthreads();   // barrier 1: x1T/cat(x1) visible to all waves

        // ---- MFMA#1 (both patches): n1^T for i-tile w ----
        #pragma unroll
        for (int P = 0; P < 2; ++P) {
            #pragma unroll
            for (int ot = 0; ot < 4; ++ot) {
                f32x4 c = {0.f, 0.f, 0.f, 0.f};
                if (hasKs0) {
                    short8 a = *(const short8*)&s_x1T[P][(16 * ot + l15) * X1TS + 8 * q];
                    c = MFMA16(a, adjB0, c);
                }
                if (hasKs1) {
                    short8 a = *(const short8*)&s_x1T[P][(16 * ot + l15) * X1TS + 8 * q + 32];
                    c = MFMA16(a, adjB1, c);
                }
                // C: col i = 16w+l15 (lane), rows o = 16ot+4q+reg -> b64 write
                short4v nv;
                nv[0] = f2bf(c[0]); nv[1] = f2bf(c[1]);
                nv[2] = f2bf(c[2]); nv[3] = f2bf(c[3]);
                *(short4v*)&s_cat[P][(16 * w + l15) * CAS + 64 + 16 * ot + 4 * q] = nv;
            }
        }
        __syncthreads();   // barrier 2: n1 consumed cross-wave

        // ---- MFMA#2 (patches sequential, acc2 reused): wave w owns o-tile w ----
        #pragma unroll
        for (int P = 0; P < 2; ++P) {
            f32x4 z = {0.f, 0.f, 0.f, 0.f};
            f32x4 acc2[4] = {z, z, z, z};
            #pragma unroll
            for (int it2 = 0; it2 < 4; ++it2) {
                short8 a2[4];
                #pragma unroll
                for (int ks = 0; ks < 4; ++ks)
                    a2[ks] = *(const short8*)&s_cat[P][(16 * it2 + l15) * CAS + 32 * ks + 8 * q];
                #pragma unroll
                for (int ks = 0; ks < 4; ++ks) {
                    acc2[it2] = MFMA16(a2[ks], whf[ks], acc2[it2]);
                    acc2[it2] = MFMA16(a2[ks], wlf[ks], acc2[it2]);
                }
            }
            float total = 0.f;
            #pragma unroll
            for (int it2 = 0; it2 < 4; ++it2) {
                float s = fmaxf(acc2[it2][0] + bo, 0.f) + fmaxf(acc2[it2][1] + bo, 0.f)
                        + fmaxf(acc2[it2][2] + bo, 0.f) + fmaxf(acc2[it2][3] + bo, 0.f);
                s += __shfl_xor(s, 16);
                s += __shfl_xor(s, 32);
                total += s;           // ((s0+s1)+s2)+s3 — same order as before
            }
            if (l < 16)
                feats[(size_t)(m0 + P * 512) * 64 + 16 * w + l15] = total;
        }
        __syncthreads();   // barrier 3 (trailing): protects x1T/cat overwrite
    }
}

// ---------------------------------------------------------------------------
// GEMM: C[M x 512] = A[M x K] @ BT[K x 512] + bias1 + bias2  (verified)
// ---------------------------------------------------------------------------
template <int K>
__launch_bounds__(256, 2)
__global__ void gemm512_kernel(const float* __restrict__ A, const float* __restrict__ BT,
                               const float* __restrict__ bias1, const float* __restrict__ bias2,
                               float* __restrict__ C) {
    constexpr int K4 = K / 4;
    __shared__ __align__(16) float s_a[64 * K];
    const int tid = threadIdx.x;
    const int m0 = blockIdx.x * 64;
    const int j0 = blockIdx.y * 128;

    const float4* Ag = (const float4*)A;
    for (int e = tid; e < 16 * K; e += 256) {
        int row = e / K4, c = e % K4;
        ((float4*)s_a)[row * K4 + (c ^ ((row >> 2) & 7))] = Ag[(size_t)(m0 + row) * K4 + c];
    }
    __syncthreads();

    const int ti = tid >> 4, tj = tid & 15;
    const int swz = ti & 7;
    const int j = j0 + tj * 8;
    const int jb = (j0 >> 2) + tj * 2;
    const float4* BT4 = (const float4*)BT;

    float4 accL[4], accH[4];
    #pragma unroll
    for (int ii = 0; ii < 4; ++ii) {
        accL[ii] = make_float4(0.f, 0.f, 0.f, 0.f);
        accH[ii] = make_float4(0.f, 0.f, 0.f, 0.f);
    }
    for (int c = 0; c < K4; ++c) {
        float4 a4[4];
        #pragma unroll
        for (int ii = 0; ii < 4; ++ii)
            a4[ii] = ((const float4*)s_a)[(4 * ti + ii) * K4 + (c ^ swz)];
        #pragma unroll
        for (int kk = 0; kk < 4; ++kk) {
            float4 b1 = BT4[(size_t)(c * 4 + kk) * 128 + jb];
            float4 b2 = BT4[(size_t)(c * 4 + kk) * 128 + jb + 1];
            #pragma unroll
            for (int ii = 0; ii < 4; ++ii) {
                float av = f4c(a4[ii], kk);
                fma4(accL[ii], av, b1);
                fma4(accH[ii], av, b2);
            }
        }
    }
    float4 bL = make_float4(bias1[j] + bias2[j], bias1[j + 1] + bias2[j + 1],
                            bias1[j + 2] + bias2[j + 2], bias1[j + 3] + bias2[j + 3]);
    float4 bH = make_float4(bias1[j + 4] + bias2[j + 4], bias1[j + 5] + bias2[j + 5],
                            bias1[j + 6] + bias2[j + 6], bias1[j + 7] + bias2[j + 7]);
    #pragma unroll
    for (int ii = 0; ii < 4; ++ii) {
        size_t row = (size_t)(m0 + 4 * ti + ii);
        float4 oL = make_float4(accL[ii].x + bL.x, accL[ii].y + bL.y,
                                accL[ii].z + bL.z, accL[ii].w + bL.w);
        float4 oH = make_float4(accH[ii].x + bH.x, accH[ii].y + bH.y,
                                accH[ii].z + bH.z, accH[ii].w + bH.w);
        ((float4*)C)[(row * 512 + j) >> 2] = oL;
        ((float4*)C)[(row * 512 + j + 4) >> 2] = oH;
    }
}

// ---------------------------------------------------------------------------
// LSTM recurrence v4: MFMA (unchanged from R14/R15).
// ---------------------------------------------------------------------------
#define HS 136    // s_h row stride in shorts (68 dwords = 4 mod 32)
#define GS 516    // s_g2 row stride in floats (516 = 4 mod 32, 16B-mult)

template <bool FINAL>
__launch_bounds__(512)
__global__ void lstm_mfma(const float* __restrict__ xg, const short* __restrict__ whhfG,
                          float* __restrict__ out0,
                          const float* __restrict__ Wc1, const float* __restrict__ bc1,
                          const float* __restrict__ Wc2, const float* __restrict__ bc2,
                          float* __restrict__ out) {
    __shared__ __align__(16) short s_h[16 * HS];    // h bf16 [m][k]
    __shared__ __align__(16) float s_g2[16 * GS];   // mfma gates fp32 [m][n]
    __shared__ __align__(16) float s_hid[16 * 68];
    const int tid = threadIdx.x;
    const int w = tid >> 6, l = tid & 63, quad = l >> 4, l15 = l & 15;
    const int b0 = blockIdx.x * 16;
    const int u = tid & 127, r0 = tid >> 7;

    short8 whf[16], wlf[16];
    #pragma unroll
    for (int nt = 0; nt < 4; ++nt)
        #pragma unroll
        for (int ks = 0; ks < 4; ++ks) {
            size_t NT = (size_t)(w * 4 + nt);
            whf[nt * 4 + ks] = *(const short8*)(whhfG + (((NT * 4 + ks) * 2 + 0) * 64 + l) * 8);
            wlf[nt * 4 + ks] = *(const short8*)(whhfG + (((NT * 4 + ks) * 2 + 1) * 64 + l) * 8);
        }

    float c[4] = {0.f, 0.f, 0.f, 0.f};
    for (int e = tid; e < 16 * HS; e += 512) s_h[e] = 0;
    __syncthreads();

    for (int t = 0; t < 31; ++t) {
        float xgv[16];
        #pragma unroll
        for (int j = 0; j < 4; ++j) {
            size_t base = ((size_t)(b0 + r0 * 4 + j) * PNUM + t) * 512 + u;
            xgv[j * 4 + 0] = xg[base];
            xgv[j * 4 + 1] = xg[base + 128];
            xgv[j * 4 + 2] = xg[base + 256];
            xgv[j * 4 + 3] = xg[base + 384];
        }

        short8 af[4];
        #pragma unroll
        for (int ks = 0; ks < 4; ++ks)
            af[ks] = *(const short8*)&s_h[l15 * HS + ks * 32 + quad * 8];
        f32x4 z = {0.f, 0.f, 0.f, 0.f};
        f32x4 acc[4] = {z, z, z, z};
        #pragma unroll
        for (int nt = 0; nt < 4; ++nt)
            #pragma unroll
            for (int ks = 0; ks < 4; ++ks) {
                acc[nt] = MFMA16(af[ks], whf[nt * 4 + ks], acc[nt]);
                acc[nt] = MFMA16(af[ks], wlf[nt * 4 + ks], acc[nt]);
            }
        #pragma unroll
        for (int nt = 0; nt < 4; ++nt) {
            int n = w * 64 + nt * 16 + l15;
            #pragma unroll
            for (int reg = 0; reg < 4; ++reg)
                s_g2[(quad * 4 + reg) * GS + n] = acc[nt][reg];
        }
        __syncthreads();

        #pragma unroll
        for (int j = 0; j < 4; ++j) {
            int rr = r0 * 4 + j;
            float gi = xgv[j * 4 + 0] + s_g2[rr * GS + u];
            float gf = xgv[j * 4 + 1] + s_g2[rr * GS + 128 + u];
            float gg = xgv[j * 4 + 2] + s_g2[rr * GS + 256 + u];
            float go = xgv[j * 4 + 3] + s_g2[rr * GS + 384 + u];
            float cn = sigf(gf) * c[j] + sigf(gi) * tanhfast(gg);
            float h = sigf(go) * tanhfast(cn);
            c[j] = cn;
            s_h[rr * HS + u] = f2bf(h);
            if (!FINAL)
                out0[((size_t)(b0 + rr) * PNUM + t) * 128 + u] = h;
        }
        __syncthreads();
    }

    if (FINAL) {
        #pragma unroll
        for (int it2 = 0; it2 < 2; ++it2) {
            int item = tid + it2 * 512;
            int rr = item >> 6, uu = item & 63;
            float acc = bc1[uu];
            const float* wv = Wc1 + (size_t)uu * 128;
            #pragma unroll 8
            for (int k = 0; k < 128; ++k) acc += wv[k] * bf2f(s_h[rr * HS + k]);
            s_hid[rr * 68 + uu] = fmaxf(acc, 0.f);
        }
        __syncthreads();
        if (tid < 176) {
            int rr = tid / 11, cc = tid % 11;
            float acc = bc2[cc];
            #pragma unroll
            for (int uu = 0; uu < 64; ++uu) acc += Wc2[cc * 64 + uu] * s_hid[rr * 68 + uu];
            out[(size_t)(b0 + rr) * 11 + cc] = acc;
        }
    }
}

// ---------------------------------------------------------------------------
extern "C" void kernel_launch(void* const* d_in, const int* in_sizes, int n_in,
                              void* d_out, int out_size, void* d_ws, size_t ws_size,
                              hipStream_t stream) {
    (void)in_sizes; (void)n_in; (void)out_size; (void)ws_size;
    const float* I    = (const float*)d_in[0];
    const float* Q    = (const float*)d_in[1];
    const float* ew   = (const float*)d_in[2];
    const float* Wn1  = (const float*)d_in[3];
    const float* bn1  = (const float*)d_in[4];
    const float* Ws1  = (const float*)d_in[5];
    const float* bs1  = (const float*)d_in[6];
    const float* Wn2  = (const float*)d_in[7];
    const float* bn2  = (const float*)d_in[8];
    const float* Ws2  = (const float*)d_in[9];
    const float* bs2  = (const float*)d_in[10];
    const float* Wih0 = (const float*)d_in[11];
    const float* Whh0 = (const float*)d_in[12];
    const float* bih0 = (const float*)d_in[13];
    const float* bhh0 = (const float*)d_in[14];
    const float* Wih1 = (const float*)d_in[15];
    const float* Whh1 = (const float*)d_in[16];
    const float* bih1 = (const float*)d_in[17];
    const float* bhh1 = (const float*)d_in[18];
    const float* Wc1  = (const float*)d_in[19];
    const float* bc1  = (const float*)d_in[20];
    const float* Wc2  = (const float*)d_in[21];
    const float* bc2  = (const float*)d_in[22];
    float* out = (float*)d_out;

    // workspace (floats): ~90.4 MB
    float* wsp   = (float*)d_ws;
    float* adjn  = wsp;                           // 4096
    float* WihT0 = adjn  + 4096;                  // 32768
    float* WihT1 = WihT0 + 32768;                 // 65536
    short* adjfG  = (short*)(WihT1 + 65536);      // 3072 shorts
    short* wcatfG = adjfG + 3072;                 // 16384 shorts
    short* whhf0G = wcatfG + 16384;               // 131072 shorts
    short* whhf1G = whhf0G + 131072;              // 131072 shorts  (=> 140800 floats total)
    float* feats = WihT1 + 65536 + 140800;        // 2031616
    float* out0  = feats + 2031616;               // 4063232
    float* xg    = out0  + 4063232;               // 16252928 (shared by both layers)

    adj_kernel<<<1, 64, 0, stream>>>(ew, adjn);
    prep_kernel<<<522, 256, 0, stream>>>(Wih0, Whh0, Wih1, Whh1, adjn, Ws2, Wn2,
                                         WihT0, WihT1, adjfG, wcatfG, whhf0G, whhf1G);
    sage_mfma<<<SGRID, 256, 0, stream>>>(I, Q, adjn, Wn1, bn1, Ws1, bs1,
                                         bn2, bs2, adjfG, wcatfG, feats);
    gemm512_kernel<64><<<dim3(496, 4), 256, 0, stream>>>(feats, WihT0, bih0, bhh0, xg);
    lstm_mfma<false><<<64, 512, 0, stream>>>(xg, whhf0G, out0,
                                             nullptr, nullptr, nullptr, nullptr, nullptr);
    gemm512_kernel<128><<<dim3(496, 4), 256, 0, stream>>>(out0, WihT1, bih1, bhh1, xg);
    lstm_mfma<true><<<64, 512, 0, stream>>>(xg, whhf1G, nullptr,
                                            Wc1, bc1, Wc2, bc2, out);
}

// Round 10
// 560.539 us; speedup vs baseline: 1.0453x; 1.0031x over previous
//
#include <hip/hip_runtime.h>
#include <hip/hip_bf16.h>
#include <math.h>

#define L_SZ 1024
#define STRIDE_ 32
#define WIN 8
#define PNUM 31
#define NPATCH 31744   // 1024 batches x 31 patches
#define SGRID 512      // 256 CU x 2 blocks/CU co-resident ((256,2)-pinned residency)

// LDS row strides (in shorts). dword strides = 36/68 = 4 mod 32 -> 2-way banks (free).
#define X1TS 72
#define CAS  136

typedef __attribute__((ext_vector_type(8))) short short8;
typedef __attribute__((ext_vector_type(4))) short short4v;
typedef __attribute__((ext_vector_type(4))) float f32x4;

#define MFMA16(a, b, c) __builtin_amdgcn_mfma_f32_16x16x32_bf16(a, b, c, 0, 0, 0)

// LDS-only barrier: __syncthreads() emits s_waitcnt vmcnt(0) lgkmcnt(0) before
// s_barrier (m97 asm), forcibly draining in-flight GLOBAL loads/stores that are
// thread-private (x0 prefetch regs, out0 stores) at every barrier. This variant
// waits only on LDS (lgkmcnt) — vmem stays in flight across the barrier; the
// compiler still inserts vmcnt waits before first USE of loaded values.
// sched_barrier(0) fences both sides so hipcc can't hoist LDS ops across the
// inline-asm wait (rule #18).
__device__ __forceinline__ void bar_lds() {
    __builtin_amdgcn_sched_barrier(0);
    asm volatile("s_waitcnt lgkmcnt(0)" ::: "memory");
    __builtin_amdgcn_s_barrier();
    __builtin_amdgcn_sched_barrier(0);
}

__device__ __forceinline__ float sigf(float x) { return 1.0f / (1.0f + __expf(-x)); }
__device__ __forceinline__ float tanhfast(float x) {
    float ax = fabsf(x);
    float t = __expf(-2.0f * ax);
    return copysignf((1.0f - t) / (1.0f + t), x);
}
__device__ __forceinline__ short f2bf(float f) {
    __hip_bfloat16 h = __float2bfloat16(f);   // RNE
    return *reinterpret_cast<short*>(&h);
}
__device__ __forceinline__ float bf2f(short s) {
    __hip_bfloat16 h = *reinterpret_cast<__hip_bfloat16*>(&s);
    return __bfloat162float(h);
}
__device__ __forceinline__ float f4c(float4 v, int k) {
    return k == 0 ? v.x : (k == 1 ? v.y : (k == 2 ? v.z : v.w));
}
__device__ __forceinline__ void fma4(float4& acc, float s, float4 v) {
    acc.x += s * v.x; acc.y += s * v.y; acc.z += s * v.z; acc.w += s * v.w;
}

// ---------------------------------------------------------------------------
// adjn[i][j] = sigmoid(ew[i][j]) * mask(|i-j|<=8, i!=j) * deg_inv[i]
// ---------------------------------------------------------------------------
__global__ void adj_kernel(const float* __restrict__ ew, float* __restrict__ adjn) {
    int i = threadIdx.x;
    if (i >= 64) return;
    float sum = 0.f;
    for (int j = 0; j < 64; ++j) {
        int d = i - j; d = d < 0 ? -d : d;
        float a = (d <= WIN && d != 0) ? sigf(ew[i * 64 + j]) : 0.f;
        sum += a;
    }
    float dinv = (sum > 0.f) ? 1.0f / sum : 0.f;
    for (int j = 0; j < 64; ++j) {
        int d = i - j; d = d < 0 ? -d : d;
        float a = (d <= WIN && d != 0) ? sigf(ew[i * 64 + j]) : 0.f;
        adjn[i * 64 + j] = a * dinv;
    }
}

// ---------------------------------------------------------------------------
// prep (unchanged from R15):
//   blocks   0..127 : Wih0T | 128..383 : Wih1T | 384..393 : sage frags
//   blocks 394..457 : Whh0 frags hi/lo | 458..521 : Whh1 frags hi/lo
// ---------------------------------------------------------------------------
__global__ void prep_kernel(const float* __restrict__ Wih0, const float* __restrict__ Whh0,
                            const float* __restrict__ Wih1, const float* __restrict__ Whh1,
                            const float* __restrict__ adjn,
                            const float* __restrict__ Ws2, const float* __restrict__ Wn2,
                            float* __restrict__ Wih0T, float* __restrict__ Wih1T,
                            short* __restrict__ adjfG, short* __restrict__ wcatfG,
                            short* __restrict__ whhf0G, short* __restrict__ whhf1G) {
    int bid = blockIdx.x, tid = threadIdx.x;
    if (bid < 128) {
        int e = bid * 256 + tid;
        int k = e >> 9, j = e & 511;
        Wih0T[e] = Wih0[j * 64 + k];
        return;
    }
    if (bid < 384) {
        int e = (bid - 128) * 256 + tid;
        int k = e >> 9, j = e & 511;
        Wih1T[e] = Wih1[j * 128 + k];
        return;
    }
    if (bid < 394) {
        int t = (bid - 384) * 256 + tid;
        if (t >= 2432) return;
        int f = t >> 6, l = t & 63;
        int q = l >> 4, l15 = l & 15;
        short8 v;
        if (f < 6) {
            const int ntT[6] = {0, 1, 1, 2, 2, 3};
            const int ksT[6] = {0, 0, 1, 0, 1, 1};
            int row = l15 + 16 * ntT[f], col = 8 * q + 32 * ksT[f];
            #pragma unroll
            for (int e = 0; e < 8; ++e)
                v[e] = f2bf(adjn[row * 64 + col + e]);
            *(short8*)(adjfG + ((size_t)f * 64 + l) * 8) = v;
        } else {
            int fi = f - 6;
            int isLo = fi >= 16;
            int ff = isLo ? fi - 16 : fi;
            int nt = ff >> 2, ks = ff & 3;
            int oo = l15 + 16 * nt;
            #pragma unroll
            for (int e = 0; e < 8; ++e) {
                int k = 32 * ks + 8 * q + e;
                float src = (k < 64) ? Ws2[oo * 64 + k] : Wn2[oo * 64 + (k - 64)];
                short hi = f2bf(src);
                v[e] = isLo ? f2bf(src - bf2f(hi)) : hi;
            }
            *(short8*)(wcatfG + ((size_t)fi * 64 + l) * 8) = v;
        }
        return;
    }
    {
        int layer = (bid < 458) ? 0 : 1;
        int base = layer ? 458 : 394;
        const float* Whh = layer ? Whh1 : Whh0;
        short* dst = layer ? whhf1G : whhf0G;
        int t = (bid - base) * 256 + tid;    // 0..16383
        int frag = t >> 6, l = t & 63;
        int hl = frag & 1, ks = (frag >> 1) & 3, NT = frag >> 3;
        int g = NT * 16 + (l & 15);
        int kbase = ks * 32 + (l >> 4) * 8;
        short8 v;
        #pragma unroll
        for (int e = 0; e < 8; ++e) {
            float src = Whh[(size_t)g * 128 + kbase + e];
            short hi = f2bf(src);
            v[e] = hl ? f2bf(src - bf2f(hi)) : hi;
        }
        *(short8*)(dst + (size_t)t * 8) = v;
    }
}

// ---------------------------------------------------------------------------
// Persistent fused SAGE, bf16 MFMA.
// R25: R24 patch-pair structure + LDS-only barriers. R24 evidence: 12.5k cyc
// per iter vs ~6.5k issued work; __syncthreads' vmcnt(0) drain completes the
// x0 prefetch ON the critical path at every barrier (3/iter) — the m97-ladder
// "barrier drain" stall. bar_lds() waits lgkmcnt only; x0 global loads stay
// in flight across barriers and get their vmcnt wait at first use (next
// iteration's phase 1). All cross-wave edges (x1T, cat) are LDS -> lgkmcnt(0)
// + s_barrier is sufficient. Math/layout/order unchanged -> bit-identical.
// R24 baseline: 184 us, VGPR 116, FETCH 8.2 MB.
// ---------------------------------------------------------------------------
__launch_bounds__(256, 2)
__global__ void sage_mfma(const float* __restrict__ I, const float* __restrict__ Q,
                          const float* __restrict__ adjn,
                          const float* __restrict__ Wn1, const float* __restrict__ bn1,
                          const float* __restrict__ Ws1, const float* __restrict__ bs1,
                          const float* __restrict__ bn2, const float* __restrict__ bs2,
                          const short* __restrict__ adjfG, const short* __restrict__ wcatfG,
                          float* __restrict__ feats) {
    __shared__ __align__(16) short s_x1T[2][64 * X1TS];  // x1^T [o][i] bf16, per patch
    __shared__ __align__(16) short s_cat[2][64 * CAS];   // [i][x1|n1] bf16, per patch

    const int tid = threadIdx.x;
    const int w = tid >> 6, l = tid & 63, q = l >> 4, l15 = l & 15;

    // adj frags for THIS wave's i-tile (band): w0:{ks0}, w1/w2:{ks0,ks1}, w3:{ks1}
    const bool hasKs0 = (w <= 2);
    const bool hasKs1 = (w >= 1);
    const int idx0 = (w == 0) ? 0 : (w == 1 ? 1 : 3);    // frag idx for (nt=w, ks=0)
    const int idx1 = (w == 1) ? 2 : (w == 2 ? 4 : 5);    // frag idx for (nt=w, ks=1)
    short8 adjB0 = {}, adjB1 = {};
    if (hasKs0) adjB0 = *(const short8*)(adjfG + ((size_t)idx0 * 64 + l) * 8);
    if (hasKs1) adjB1 = *(const short8*)(adjfG + ((size_t)idx1 * 64 + l) * 8);

    // weight frags for THIS wave's o-tile (nt = w): 8 frags = 32 VGPRs
    short8 whf[4], wlf[4];
    #pragma unroll
    for (int ks = 0; ks < 4; ++ks) {
        whf[ks] = *(const short8*)(wcatfG + ((size_t)(w * 4 + ks) * 64 + l) * 8);
        wlf[ks] = *(const short8*)(wcatfG + ((size_t)(w * 4 + ks + 16) * 64 + l) * 8);
    }
    // bias for this wave's output channel (loop-invariant)
    const int oo = l15 + 16 * w;
    const float bo = bs2[oo] + bn2[oo];

    // adjn band in registers: lane l = row i; zeros outside [0,64)
    float areg[17];
    #pragma unroll
    for (int d = 0; d < 17; ++d) {
        int j = l + d - WIN;
        areg[d] = (j >= 0 && j < 64) ? adjn[l * 64 + j] : 0.f;
    }

    // preload iter-0 x0 for both patches (lane l holds column i = l)
    float x0a[2], x0b[2];
    #pragma unroll
    for (int P = 0; P < 2; ++P) {
        int m = blockIdx.x + P * 512;
        int b = m / PNUM, p = m % PNUM;
        x0a[P] = I[(size_t)b * L_SZ + p * STRIDE_ + l];
        x0b[P] = Q[(size_t)b * L_SZ + p * STRIDE_ + l];
    }

    for (int it = 0; it < 31; ++it) {
        const int m0 = it * 1024 + blockIdx.x;

        // ---- Phase 1 (both patches): n0 via shuffles, x1 = relu(...) ----
        #pragma unroll
        for (int P = 0; P < 2; ++P) {
            float n0a = 0.f, n0b = 0.f;
            #pragma unroll
            for (int d = 0; d < 17; ++d) {
                int j = l + d - WIN;
                float xa = __shfl(x0a[P], j, 64);
                float xb = __shfl(x0b[P], j, 64);
                n0a += areg[d] * xa;          // out-of-band areg == 0.0f exactly
                n0b += areg[d] * xb;
            }
            union { short s[16]; short8 v[2]; } pk;
            #pragma unroll
            for (int t = 0; t < 16; ++t) {
                int o = w * 16 + t;
                float2 wsv = ((const float2*)Ws1)[o];
                float2 wnv = ((const float2*)Wn1)[o];
                float v = bs1[o] + bn1[o] + wsv.x * x0a[P] + wsv.y * x0b[P]
                                          + wnv.x * n0a + wnv.y * n0b;
                v = fmaxf(v, 0.f);
                short bv = f2bf(v);
                s_x1T[P][o * X1TS + l] = bv;
                pk.s[t] = bv;
            }
            *(short8*)&s_cat[P][l * CAS + w * 16]     = pk.v[0];
            *(short8*)&s_cat[P][l * CAS + w * 16 + 8] = pk.v[1];
        }

        // issue next-iter x0 loads now — with bar_lds they stay in flight
        // across all three barriers and complete under the MFMA phases
        if (it + 1 < 31) {
            #pragma unroll
            for (int P = 0; P < 2; ++P) {
                int m = (it + 1) * 1024 + blockIdx.x + P * 512;
                int b = m / PNUM, p = m % PNUM;
                x0a[P] = I[(size_t)b * L_SZ + p * STRIDE_ + l];
                x0b[P] = Q[(size_t)b * L_SZ + p * STRIDE_ + l];
            }
        }
        bar_lds();   // barrier 1: x1T/cat(x1) visible to all waves (LDS only)

        // ---- MFMA#1 (both patches): n1^T for i-tile w ----
        #pragma unroll
        for (int P = 0; P < 2; ++P) {
            #pragma unroll
            for (int ot = 0; ot < 4; ++ot) {
                f32x4 c = {0.f, 0.f, 0.f, 0.f};
                if (hasKs0) {
                    short8 a = *(const short8*)&s_x1T[P][(16 * ot + l15) * X1TS + 8 * q];
                    c = MFMA16(a, adjB0, c);
                }
                if (hasKs1) {
                    short8 a = *(const short8*)&s_x1T[P][(16 * ot + l15) * X1TS + 8 * q + 32];
                    c = MFMA16(a, adjB1, c);
                }
                // C: col i = 16w+l15 (lane), rows o = 16ot+4q+reg -> b64 write
                short4v nv;
                nv[0] = f2bf(c[0]); nv[1] = f2bf(c[1]);
                nv[2] = f2bf(c[2]); nv[3] = f2bf(c[3]);
                *(short4v*)&s_cat[P][(16 * w + l15) * CAS + 64 + 16 * ot + 4 * q] = nv;
            }
        }
        bar_lds();   // barrier 2: n1 consumed cross-wave

        // ---- MFMA#2 (patches sequential, acc2 reused): wave w owns o-tile w ----
        #pragma unroll
        for (int P = 0; P < 2; ++P) {
            f32x4 z = {0.f, 0.f, 0.f, 0.f};
            f32x4 acc2[4] = {z, z, z, z};
            #pragma unroll
            for (int it2 = 0; it2 < 4; ++it2) {
                short8 a2[4];
                #pragma unroll
                for (int ks = 0; ks < 4; ++ks)
                    a2[ks] = *(const short8*)&s_cat[P][(16 * it2 + l15) * CAS + 32 * ks + 8 * q];
                #pragma unroll
                for (int ks = 0; ks < 4; ++ks) {
                    acc2[it2] = MFMA16(a2[ks], whf[ks], acc2[it2]);
                    acc2[it2] = MFMA16(a2[ks], wlf[ks], acc2[it2]);
                }
            }
            float total = 0.f;
            #pragma unroll
            for (int it2 = 0; it2 < 4; ++it2) {
                float s = fmaxf(acc2[it2][0] + bo, 0.f) + fmaxf(acc2[it2][1] + bo, 0.f)
                        + fmaxf(acc2[it2][2] + bo, 0.f) + fmaxf(acc2[it2][3] + bo, 0.f);
                s += __shfl_xor(s, 16);
                s += __shfl_xor(s, 32);
                total += s;           // ((s0+s1)+s2)+s3 — same order as before
            }
            if (l < 16)
                feats[(size_t)(m0 + P * 512) * 64 + 16 * w + l15] = total;
        }
        bar_lds();   // barrier 3 (trailing): protects x1T/cat overwrite
    }
}

// ---------------------------------------------------------------------------
// GEMM: C[M x 512] = A[M x K] @ BT[K x 512] + bias1 + bias2  (verified)
// ---------------------------------------------------------------------------
template <int K>
__launch_bounds__(256, 2)
__global__ void gemm512_kernel(const float* __restrict__ A, const float* __restrict__ BT,
                               const float* __restrict__ bias1, const float* __restrict__ bias2,
                               float* __restrict__ C) {
    constexpr int K4 = K / 4;
    __shared__ __align__(16) float s_a[64 * K];
    const int tid = threadIdx.x;
    const int m0 = blockIdx.x * 64;
    const int j0 = blockIdx.y * 128;

    const float4* Ag = (const float4*)A;
    for (int e = tid; e < 16 * K; e += 256) {
        int row = e / K4, c = e % K4;
        ((float4*)s_a)[row * K4 + (c ^ ((row >> 2) & 7))] = Ag[(size_t)(m0 + row) * K4 + c];
    }
    __syncthreads();

    const int ti = tid >> 4, tj = tid & 15;
    const int swz = ti & 7;
    const int j = j0 + tj * 8;
    const int jb = (j0 >> 2) + tj * 2;
    const float4* BT4 = (const float4*)BT;

    float4 accL[4], accH[4];
    #pragma unroll
    for (int ii = 0; ii < 4; ++ii) {
        accL[ii] = make_float4(0.f, 0.f, 0.f, 0.f);
        accH[ii] = make_float4(0.f, 0.f, 0.f, 0.f);
    }
    for (int c = 0; c < K4; ++c) {
        float4 a4[4];
        #pragma unroll
        for (int ii = 0; ii < 4; ++ii)
            a4[ii] = ((const float4*)s_a)[(4 * ti + ii) * K4 + (c ^ swz)];
        #pragma unroll
        for (int kk = 0; kk < 4; ++kk) {
            float4 b1 = BT4[(size_t)(c * 4 + kk) * 128 + jb];
            float4 b2 = BT4[(size_t)(c * 4 + kk) * 128 + jb + 1];
            #pragma unroll
            for (int ii = 0; ii < 4; ++ii) {
                float av = f4c(a4[ii], kk);
                fma4(accL[ii], av, b1);
                fma4(accH[ii], av, b2);
            }
        }
    }
    float4 bL = make_float4(bias1[j] + bias2[j], bias1[j + 1] + bias2[j + 1],
                            bias1[j + 2] + bias2[j + 2], bias1[j + 3] + bias2[j + 3]);
    float4 bH = make_float4(bias1[j + 4] + bias2[j + 4], bias1[j + 5] + bias2[j + 5],
                            bias1[j + 6] + bias2[j + 6], bias1[j + 7] + bias2[j + 7]);
    #pragma unroll
    for (int ii = 0; ii < 4; ++ii) {
        size_t row = (size_t)(m0 + 4 * ti + ii);
        float4 oL = make_float4(accL[ii].x + bL.x, accL[ii].y + bL.y,
                                accL[ii].z + bL.z, accL[ii].w + bL.w);
        float4 oH = make_float4(accH[ii].x + bH.x, accH[ii].y + bH.y,
                                accH[ii].z + bH.z, accH[ii].w + bH.w);
        ((float4*)C)[(row * 512 + j) >> 2] = oL;
        ((float4*)C)[(row * 512 + j + 4) >> 2] = oH;
    }
}

// ---------------------------------------------------------------------------
// LSTM recurrence v5: MFMA + LDS-only barriers. The per-step __syncthreads
// drained the out0 global stores and xgv loads (vmcnt(0)) 2x per timestep;
// neither is consumed across the barrier (out0 read by a LATER kernel, xgv
// thread-private). bar_lds() keeps them in flight. s_h/s_g2 edges are LDS ->
// lgkmcnt(0)+s_barrier sufficient. Math unchanged -> bit-identical.
// ---------------------------------------------------------------------------
#define HS 136    // s_h row stride in shorts (68 dwords = 4 mod 32)
#define GS 516    // s_g2 row stride in floats (516 = 4 mod 32, 16B-mult)

template <bool FINAL>
__launch_bounds__(512)
__global__ void lstm_mfma(const float* __restrict__ xg, const short* __restrict__ whhfG,
                          float* __restrict__ out0,
                          const float* __restrict__ Wc1, const float* __restrict__ bc1,
                          const float* __restrict__ Wc2, const float* __restrict__ bc2,
                          float* __restrict__ out) {
    __shared__ __align__(16) short s_h[16 * HS];    // h bf16 [m][k]
    __shared__ __align__(16) float s_g2[16 * GS];   // mfma gates fp32 [m][n]
    __shared__ __align__(16) float s_hid[16 * 68];
    const int tid = threadIdx.x;
    const int w = tid >> 6, l = tid & 63, quad = l >> 4, l15 = l & 15;
    const int b0 = blockIdx.x * 16;
    const int u = tid & 127, r0 = tid >> 7;

    short8 whf[16], wlf[16];
    #pragma unroll
    for (int nt = 0; nt < 4; ++nt)
        #pragma unroll
        for (int ks = 0; ks < 4; ++ks) {
            size_t NT = (size_t)(w * 4 + nt);
            whf[nt * 4 + ks] = *(const short8*)(whhfG + (((NT * 4 + ks) * 2 + 0) * 64 + l) * 8);
            wlf[nt * 4 + ks] = *(const short8*)(whhfG + (((NT * 4 + ks) * 2 + 1) * 64 + l) * 8);
        }

    float c[4] = {0.f, 0.f, 0.f, 0.f};
    for (int e = tid; e < 16 * HS; e += 512) s_h[e] = 0;
    __syncthreads();

    for (int t = 0; t < 31; ++t) {
        float xgv[16];
        #pragma unroll
        for (int j = 0; j < 4; ++j) {
            size_t base = ((size_t)(b0 + r0 * 4 + j) * PNUM + t) * 512 + u;
            xgv[j * 4 + 0] = xg[base];
            xgv[j * 4 + 1] = xg[base + 128];
            xgv[j * 4 + 2] = xg[base + 256];
            xgv[j * 4 + 3] = xg[base + 384];
        }

        short8 af[4];
        #pragma unroll
        for (int ks = 0; ks < 4; ++ks)
            af[ks] = *(const short8*)&s_h[l15 * HS + ks * 32 + quad * 8];
        f32x4 z = {0.f, 0.f, 0.f, 0.f};
        f32x4 acc[4] = {z, z, z, z};
        #pragma unroll
        for (int nt = 0; nt < 4; ++nt)
            #pragma unroll
            for (int ks = 0; ks < 4; ++ks) {
                acc[nt] = MFMA16(af[ks], whf[nt * 4 + ks], acc[nt]);
                acc[nt] = MFMA16(af[ks], wlf[nt * 4 + ks], acc[nt]);
            }
        #pragma unroll
        for (int nt = 0; nt < 4; ++nt) {
            int n = w * 64 + nt * 16 + l15;
            #pragma unroll
            for (int reg = 0; reg < 4; ++reg)
                s_g2[(quad * 4 + reg) * GS + n] = acc[nt][reg];
        }
        bar_lds();

        #pragma unroll
        for (int j = 0; j < 4; ++j) {
            int rr = r0 * 4 + j;
            float gi = xgv[j * 4 + 0] + s_g2[rr * GS + u];
            float gf = xgv[j * 4 + 1] + s_g2[rr * GS + 128 + u];
            float gg = xgv[j * 4 + 2] + s_g2[rr * GS + 256 + u];
            float go = xgv[j * 4 + 3] + s_g2[rr * GS + 384 + u];
            float cn = sigf(gf) * c[j] + sigf(gi) * tanhfast(gg);
            float h = sigf(go) * tanhfast(cn);
            c[j] = cn;
            s_h[rr * HS + u] = f2bf(h);
            if (!FINAL)
                out0[((size_t)(b0 + rr) * PNUM + t) * 128 + u] = h;
        }
        bar_lds();
    }

    if (FINAL) {
        #pragma unroll
        for (int it2 = 0; it2 < 2; ++it2) {
            int item = tid + it2 * 512;
            int rr = item >> 6, uu = item & 63;
            float acc = bc1[uu];
            const float* wv = Wc1 + (size_t)uu * 128;
            #pragma unroll 8
            for (int k = 0; k < 128; ++k) acc += wv[k] * bf2f(s_h[rr * HS + k]);
            s_hid[rr * 68 + uu] = fmaxf(acc, 0.f);
        }
        __syncthreads();
        if (tid < 176) {
            int rr = tid / 11, cc = tid % 11;
            float acc = bc2[cc];
            #pragma unroll
            for (int uu = 0; uu < 64; ++uu) acc += Wc2[cc * 64 + uu] * s_hid[rr * 68 + uu];
            out[(size_t)(b0 + rr) * 11 + cc] = acc;
        }
    }
}

// ---------------------------------------------------------------------------
extern "C" void kernel_launch(void* const* d_in, const int* in_sizes, int n_in,
                              void* d_out, int out_size, void* d_ws, size_t ws_size,
                              hipStream_t stream) {
    (void)in_sizes; (void)n_in; (void)out_size; (void)ws_size;
    const float* I    = (const float*)d_in[0];
    const float* Q    = (const float*)d_in[1];
    const float* ew   = (const float*)d_in[2];
    const float* Wn1  = (const float*)d_in[3];
    const float* bn1  = (const float*)d_in[4];
    const float* Ws1  = (const float*)d_in[5];
    const float* bs1  = (const float*)d_in[6];
    const float* Wn2  = (const float*)d_in[7];
    const float* bn2  = (const float*)d_in[8];
    const float* Ws2  = (const float*)d_in[9];
    const float* bs2  = (const float*)d_in[10];
    const float* Wih0 = (const float*)d_in[11];
    const float* Whh0 = (const float*)d_in[12];
    const float* bih0 = (const float*)d_in[13];
    const float* bhh0 = (const float*)d_in[14];
    const float* Wih1 = (const float*)d_in[15];
    const float* Whh1 = (const float*)d_in[16];
    const float* bih1 = (const float*)d_in[17];
    const float* bhh1 = (const float*)d_in[18];
    const float* Wc1  = (const float*)d_in[19];
    const float* bc1  = (const float*)d_in[20];
    const float* Wc2  = (const float*)d_in[21];
    const float* bc2  = (const float*)d_in[22];
    float* out = (float*)d_out;

    // workspace (floats): ~90.4 MB
    float* wsp   = (float*)d_ws;
    float* adjn  = wsp;                           // 4096
    float* WihT0 = adjn  + 4096;                  // 32768
    float* WihT1 = WihT0 + 32768;                 // 65536
    short* adjfG  = (short*)(WihT1 + 65536);      // 3072 shorts
    short* wcatfG = adjfG + 3072;                 // 16384 shorts
    short* whhf0G = wcatfG + 16384;               // 131072 shorts
    short* whhf1G = whhf0G + 131072;              // 131072 shorts  (=> 140800 floats total)
    float* feats = WihT1 + 65536 + 140800;        // 2031616
    float* out0  = feats + 2031616;               // 4063232
    float* xg    = out0  + 4063232;               // 16252928 (shared by both layers)

    adj_kernel<<<1, 64, 0, stream>>>(ew, adjn);
    prep_kernel<<<522, 256, 0, stream>>>(Wih0, Whh0, Wih1, Whh1, adjn, Ws2, Wn2,
                                         WihT0, WihT1, adjfG, wcatfG, whhf0G, whhf1G);
    sage_mfma<<<SGRID, 256, 0, stream>>>(I, Q, adjn, Wn1, bn1, Ws1, bs1,
                                         bn2, bs2, adjfG, wcatfG, feats);
    gemm512_kernel<64><<<dim3(496, 4), 256, 0, stream>>>(feats, WihT0, bih0, bhh0, xg);
    lstm_mfma<false><<<64, 512, 0, stream>>>(xg, whhf0G, out0,
                                             nullptr, nullptr, nullptr, nullptr, nullptr);
    gemm512_kernel<128><<<dim3(496, 4), 256, 0, stream>>>(out0, WihT1, bih1, bhh1, xg);
    lstm_mfma<true><<<64, 512, 0, stream>>>(xg, whhf1G, nullptr,
                                            Wc1, bc1, Wc2, bc2, out);
}

// Round 11
// 488.605 us; speedup vs baseline: 1.1991x; 1.1472x over previous
//
#include <hip/hip_runtime.h>
#include <hip/hip_bf16.h>
#include <math.h>

#define L_SZ 1024
#define STRIDE_ 32
#define WIN 8
#define PNUM 31
#define NPATCH 31744   // 1024 batches x 31 patches
#define SGRID 512      // 256 CU x 2 blocks/CU co-resident ((256,2)-pinned residency)

// LDS row strides (in shorts). dword strides = 36/68 = 4 mod 32 -> 2-way banks (free).
#define X1TS 72
#define CAS  136

typedef __attribute__((ext_vector_type(8))) short short8;
typedef __attribute__((ext_vector_type(4))) short short4v;
typedef __attribute__((ext_vector_type(4))) float f32x4;

#define MFMA16(a, b, c) __builtin_amdgcn_mfma_f32_16x16x32_bf16(a, b, c, 0, 0, 0)

// LDS-only barrier: waits lgkmcnt only; vmem stays in flight across the
// barrier (compiler inserts vmcnt waits before first USE of loaded values).
// sched_barrier(0) fences both sides (rule #18).
__device__ __forceinline__ void bar_lds() {
    __builtin_amdgcn_sched_barrier(0);
    asm volatile("s_waitcnt lgkmcnt(0)" ::: "memory");
    __builtin_amdgcn_s_barrier();
    __builtin_amdgcn_sched_barrier(0);
}

__device__ __forceinline__ float sigf(float x) { return 1.0f / (1.0f + __expf(-x)); }
__device__ __forceinline__ float tanhfast(float x) {
    float ax = fabsf(x);
    float t = __expf(-2.0f * ax);
    return copysignf((1.0f - t) / (1.0f + t), x);
}
__device__ __forceinline__ short f2bf(float f) {
    __hip_bfloat16 h = __float2bfloat16(f);   // RNE
    return *reinterpret_cast<short*>(&h);
}
__device__ __forceinline__ float bf2f(short s) {
    __hip_bfloat16 h = *reinterpret_cast<__hip_bfloat16*>(&s);
    return __bfloat162float(h);
}
__device__ __forceinline__ float f4c(float4 v, int k) {
    return k == 0 ? v.x : (k == 1 ? v.y : (k == 2 ? v.z : v.w));
}
__device__ __forceinline__ void fma4(float4& acc, float s, float4 v) {
    acc.x += s * v.x; acc.y += s * v.y; acc.z += s * v.z; acc.w += s * v.w;
}

// ---------------------------------------------------------------------------
// adjn[i][j] = sigmoid(ew[i][j]) * mask(|i-j|<=8, i!=j) * deg_inv[i]
// ---------------------------------------------------------------------------
__global__ void adj_kernel(const float* __restrict__ ew, float* __restrict__ adjn) {
    int i = threadIdx.x;
    if (i >= 64) return;
    float sum = 0.f;
    for (int j = 0; j < 64; ++j) {
        int d = i - j; d = d < 0 ? -d : d;
        float a = (d <= WIN && d != 0) ? sigf(ew[i * 64 + j]) : 0.f;
        sum += a;
    }
    float dinv = (sum > 0.f) ? 1.0f / sum : 0.f;
    for (int j = 0; j < 64; ++j) {
        int d = i - j; d = d < 0 ? -d : d;
        float a = (d <= WIN && d != 0) ? sigf(ew[i * 64 + j]) : 0.f;
        adjn[i * 64 + j] = a * dinv;
    }
}

// ---------------------------------------------------------------------------
// prep (unchanged from R15):
//   blocks   0..127 : Wih0T | 128..383 : Wih1T | 384..393 : sage frags
//   blocks 394..457 : Whh0 frags hi/lo | 458..521 : Whh1 frags hi/lo
// ---------------------------------------------------------------------------
__global__ void prep_kernel(const float* __restrict__ Wih0, const float* __restrict__ Whh0,
                            const float* __restrict__ Wih1, const float* __restrict__ Whh1,
                            const float* __restrict__ adjn,
                            const float* __restrict__ Ws2, const float* __restrict__ Wn2,
                            float* __restrict__ Wih0T, float* __restrict__ Wih1T,
                            short* __restrict__ adjfG, short* __restrict__ wcatfG,
                            short* __restrict__ whhf0G, short* __restrict__ whhf1G) {
    int bid = blockIdx.x, tid = threadIdx.x;
    if (bid < 128) {
        int e = bid * 256 + tid;
        int k = e >> 9, j = e & 511;
        Wih0T[e] = Wih0[j * 64 + k];
        return;
    }
    if (bid < 384) {
        int e = (bid - 128) * 256 + tid;
        int k = e >> 9, j = e & 511;
        Wih1T[e] = Wih1[j * 128 + k];
        return;
    }
    if (bid < 394) {
        int t = (bid - 384) * 256 + tid;
        if (t >= 2432) return;
        int f = t >> 6, l = t & 63;
        int q = l >> 4, l15 = l & 15;
        short8 v;
        if (f < 6) {
            const int ntT[6] = {0, 1, 1, 2, 2, 3};
            const int ksT[6] = {0, 0, 1, 0, 1, 1};
            int row = l15 + 16 * ntT[f], col = 8 * q + 32 * ksT[f];
            #pragma unroll
            for (int e = 0; e < 8; ++e)
                v[e] = f2bf(adjn[row * 64 + col + e]);
            *(short8*)(adjfG + ((size_t)f * 64 + l) * 8) = v;
        } else {
            int fi = f - 6;
            int isLo = fi >= 16;
            int ff = isLo ? fi - 16 : fi;
            int nt = ff >> 2, ks = ff & 3;
            int oo = l15 + 16 * nt;
            #pragma unroll
            for (int e = 0; e < 8; ++e) {
                int k = 32 * ks + 8 * q + e;
                float src = (k < 64) ? Ws2[oo * 64 + k] : Wn2[oo * 64 + (k - 64)];
                short hi = f2bf(src);
                v[e] = isLo ? f2bf(src - bf2f(hi)) : hi;
            }
            *(short8*)(wcatfG + ((size_t)fi * 64 + l) * 8) = v;
        }
        return;
    }
    {
        int layer = (bid < 458) ? 0 : 1;
        int base = layer ? 458 : 394;
        const float* Whh = layer ? Whh1 : Whh0;
        short* dst = layer ? whhf1G : whhf0G;
        int t = (bid - base) * 256 + tid;    // 0..16383
        int frag = t >> 6, l = t & 63;
        int hl = frag & 1, ks = (frag >> 1) & 3, NT = frag >> 3;
        int g = NT * 16 + (l & 15);
        int kbase = ks * 32 + (l >> 4) * 8;
        short8 v;
        #pragma unroll
        for (int e = 0; e < 8; ++e) {
            float src = Whh[(size_t)g * 128 + kbase + e];
            short hi = f2bf(src);
            v[e] = hl ? f2bf(src - bf2f(hi)) : hi;
        }
        *(short8*)(dst + (size_t)t * 8) = v;
    }
}

// ---------------------------------------------------------------------------
// Persistent fused SAGE, bf16 MFMA. (R25 structure — plateaued at 182 us;
// left untouched this round as control.)
// ---------------------------------------------------------------------------
__launch_bounds__(256, 2)
__global__ void sage_mfma(const float* __restrict__ I, const float* __restrict__ Q,
                          const float* __restrict__ adjn,
                          const float* __restrict__ Wn1, const float* __restrict__ bn1,
                          const float* __restrict__ Ws1, const float* __restrict__ bs1,
                          const float* __restrict__ bn2, const float* __restrict__ bs2,
                          const short* __restrict__ adjfG, const short* __restrict__ wcatfG,
                          float* __restrict__ feats) {
    __shared__ __align__(16) short s_x1T[2][64 * X1TS];  // x1^T [o][i] bf16, per patch
    __shared__ __align__(16) short s_cat[2][64 * CAS];   // [i][x1|n1] bf16, per patch

    const int tid = threadIdx.x;
    const int w = tid >> 6, l = tid & 63, q = l >> 4, l15 = l & 15;

    // adj frags for THIS wave's i-tile (band): w0:{ks0}, w1/w2:{ks0,ks1}, w3:{ks1}
    const bool hasKs0 = (w <= 2);
    const bool hasKs1 = (w >= 1);
    const int idx0 = (w == 0) ? 0 : (w == 1 ? 1 : 3);    // frag idx for (nt=w, ks=0)
    const int idx1 = (w == 1) ? 2 : (w == 2 ? 4 : 5);    // frag idx for (nt=w, ks=1)
    short8 adjB0 = {}, adjB1 = {};
    if (hasKs0) adjB0 = *(const short8*)(adjfG + ((size_t)idx0 * 64 + l) * 8);
    if (hasKs1) adjB1 = *(const short8*)(adjfG + ((size_t)idx1 * 64 + l) * 8);

    // weight frags for THIS wave's o-tile (nt = w): 8 frags = 32 VGPRs
    short8 whf[4], wlf[4];
    #pragma unroll
    for (int ks = 0; ks < 4; ++ks) {
        whf[ks] = *(const short8*)(wcatfG + ((size_t)(w * 4 + ks) * 64 + l) * 8);
        wlf[ks] = *(const short8*)(wcatfG + ((size_t)(w * 4 + ks + 16) * 64 + l) * 8);
    }
    // bias for this wave's output channel (loop-invariant)
    const int oo = l15 + 16 * w;
    const float bo = bs2[oo] + bn2[oo];

    // adjn band in registers: lane l = row i; zeros outside [0,64)
    float areg[17];
    #pragma unroll
    for (int d = 0; d < 17; ++d) {
        int j = l + d - WIN;
        areg[d] = (j >= 0 && j < 64) ? adjn[l * 64 + j] : 0.f;
    }

    // preload iter-0 x0 for both patches (lane l holds column i = l)
    float x0a[2], x0b[2];
    #pragma unroll
    for (int P = 0; P < 2; ++P) {
        int m = blockIdx.x + P * 512;
        int b = m / PNUM, p = m % PNUM;
        x0a[P] = I[(size_t)b * L_SZ + p * STRIDE_ + l];
        x0b[P] = Q[(size_t)b * L_SZ + p * STRIDE_ + l];
    }

    for (int it = 0; it < 31; ++it) {
        const int m0 = it * 1024 + blockIdx.x;

        // ---- Phase 1 (both patches): n0 via shuffles, x1 = relu(...) ----
        #pragma unroll
        for (int P = 0; P < 2; ++P) {
            float n0a = 0.f, n0b = 0.f;
            #pragma unroll
            for (int d = 0; d < 17; ++d) {
                int j = l + d - WIN;
                float xa = __shfl(x0a[P], j, 64);
                float xb = __shfl(x0b[P], j, 64);
                n0a += areg[d] * xa;          // out-of-band areg == 0.0f exactly
                n0b += areg[d] * xb;
            }
            union { short s[16]; short8 v[2]; } pk;
            #pragma unroll
            for (int t = 0; t < 16; ++t) {
                int o = w * 16 + t;
                float2 wsv = ((const float2*)Ws1)[o];
                float2 wnv = ((const float2*)Wn1)[o];
                float v = bs1[o] + bn1[o] + wsv.x * x0a[P] + wsv.y * x0b[P]
                                          + wnv.x * n0a + wnv.y * n0b;
                v = fmaxf(v, 0.f);
                short bv = f2bf(v);
                s_x1T[P][o * X1TS + l] = bv;
                pk.s[t] = bv;
            }
            *(short8*)&s_cat[P][l * CAS + w * 16]     = pk.v[0];
            *(short8*)&s_cat[P][l * CAS + w * 16 + 8] = pk.v[1];
        }

        // issue next-iter x0 loads now — stay in flight across barriers
        if (it + 1 < 31) {
            #pragma unroll
            for (int P = 0; P < 2; ++P) {
                int m = (it + 1) * 1024 + blockIdx.x + P * 512;
                int b = m / PNUM, p = m % PNUM;
                x0a[P] = I[(size_t)b * L_SZ + p * STRIDE_ + l];
                x0b[P] = Q[(size_t)b * L_SZ + p * STRIDE_ + l];
            }
        }
        bar_lds();   // barrier 1: x1T/cat(x1) visible to all waves (LDS only)

        // ---- MFMA#1 (both patches): n1^T for i-tile w ----
        #pragma unroll
        for (int P = 0; P < 2; ++P) {
            #pragma unroll
            for (int ot = 0; ot < 4; ++ot) {
                f32x4 c = {0.f, 0.f, 0.f, 0.f};
                if (hasKs0) {
                    short8 a = *(const short8*)&s_x1T[P][(16 * ot + l15) * X1TS + 8 * q];
                    c = MFMA16(a, adjB0, c);
                }
                if (hasKs1) {
                    short8 a = *(const short8*)&s_x1T[P][(16 * ot + l15) * X1TS + 8 * q + 32];
                    c = MFMA16(a, adjB1, c);
                }
                // C: col i = 16w+l15 (lane), rows o = 16ot+4q+reg -> b64 write
                short4v nv;
                nv[0] = f2bf(c[0]); nv[1] = f2bf(c[1]);
                nv[2] = f2bf(c[2]); nv[3] = f2bf(c[3]);
                *(short4v*)&s_cat[P][(16 * w + l15) * CAS + 64 + 16 * ot + 4 * q] = nv;
            }
        }
        bar_lds();   // barrier 2: n1 consumed cross-wave

        // ---- MFMA#2 (patches sequential, acc2 reused): wave w owns o-tile w ----
        #pragma unroll
        for (int P = 0; P < 2; ++P) {
            f32x4 z = {0.f, 0.f, 0.f, 0.f};
            f32x4 acc2[4] = {z, z, z, z};
            #pragma unroll
            for (int it2 = 0; it2 < 4; ++it2) {
                short8 a2[4];
                #pragma unroll
                for (int ks = 0; ks < 4; ++ks)
                    a2[ks] = *(const short8*)&s_cat[P][(16 * it2 + l15) * CAS + 32 * ks + 8 * q];
                #pragma unroll
                for (int ks = 0; ks < 4; ++ks) {
                    acc2[it2] = MFMA16(a2[ks], whf[ks], acc2[it2]);
                    acc2[it2] = MFMA16(a2[ks], wlf[ks], acc2[it2]);
                }
            }
            float total = 0.f;
            #pragma unroll
            for (int it2 = 0; it2 < 4; ++it2) {
                float s = fmaxf(acc2[it2][0] + bo, 0.f) + fmaxf(acc2[it2][1] + bo, 0.f)
                        + fmaxf(acc2[it2][2] + bo, 0.f) + fmaxf(acc2[it2][3] + bo, 0.f);
                s += __shfl_xor(s, 16);
                s += __shfl_xor(s, 32);
                total += s;           // ((s0+s1)+s2)+s3 — same order as before
            }
            if (l < 16)
                feats[(size_t)(m0 + P * 512) * 64 + 16 * w + l15] = total;
        }
        bar_lds();   // barrier 3 (trailing): protects x1T/cat overwrite
    }
}

// ---------------------------------------------------------------------------
// GEMM: C[M x 512] = A[M x K] @ BT[K x 512] + bias1 + bias2  (verified)
// ---------------------------------------------------------------------------
template <int K>
__launch_bounds__(256, 2)
__global__ void gemm512_kernel(const float* __restrict__ A, const float* __restrict__ BT,
                               const float* __restrict__ bias1, const float* __restrict__ bias2,
                               float* __restrict__ C) {
    constexpr int K4 = K / 4;
    __shared__ __align__(16) float s_a[64 * K];
    const int tid = threadIdx.x;
    const int m0 = blockIdx.x * 64;
    const int j0 = blockIdx.y * 128;

    const float4* Ag = (const float4*)A;
    for (int e = tid; e < 16 * K; e += 256) {
        int row = e / K4, c = e % K4;
        ((float4*)s_a)[row * K4 + (c ^ ((row >> 2) & 7))] = Ag[(size_t)(m0 + row) * K4 + c];
    }
    __syncthreads();

    const int ti = tid >> 4, tj = tid & 15;
    const int swz = ti & 7;
    const int j = j0 + tj * 8;
    const int jb = (j0 >> 2) + tj * 2;
    const float4* BT4 = (const float4*)BT;

    float4 accL[4], accH[4];
    #pragma unroll
    for (int ii = 0; ii < 4; ++ii) {
        accL[ii] = make_float4(0.f, 0.f, 0.f, 0.f);
        accH[ii] = make_float4(0.f, 0.f, 0.f, 0.f);
    }
    for (int c = 0; c < K4; ++c) {
        float4 a4[4];
        #pragma unroll
        for (int ii = 0; ii < 4; ++ii)
            a4[ii] = ((const float4*)s_a)[(4 * ti + ii) * K4 + (c ^ swz)];
        #pragma unroll
        for (int kk = 0; kk < 4; ++kk) {
            float4 b1 = BT4[(size_t)(c * 4 + kk) * 128 + jb];
            float4 b2 = BT4[(size_t)(c * 4 + kk) * 128 + jb + 1];
            #pragma unroll
            for (int ii = 0; ii < 4; ++ii) {
                float av = f4c(a4[ii], kk);
                fma4(accL[ii], av, b1);
                fma4(accH[ii], av, b2);
            }
        }
    }
    float4 bL = make_float4(bias1[j] + bias2[j], bias1[j + 1] + bias2[j + 1],
                            bias1[j + 2] + bias2[j + 2], bias1[j + 3] + bias2[j + 3]);
    float4 bH = make_float4(bias1[j + 4] + bias2[j + 4], bias1[j + 5] + bias2[j + 5],
                            bias1[j + 6] + bias2[j + 6], bias1[j + 7] + bias2[j + 7]);
    #pragma unroll
    for (int ii = 0; ii < 4; ++ii) {
        size_t row = (size_t)(m0 + 4 * ti + ii);
        float4 oL = make_float4(accL[ii].x + bL.x, accL[ii].y + bL.y,
                                accL[ii].z + bL.z, accL[ii].w + bL.w);
        float4 oH = make_float4(accH[ii].x + bH.x, accH[ii].y + bH.y,
                                accH[ii].z + bH.z, accH[ii].w + bH.w);
        ((float4*)C)[(row * 512 + j) >> 2] = oL;
        ((float4*)C)[(row * 512 + j + 4) >> 2] = oH;
    }
}

// ---------------------------------------------------------------------------
// LSTM recurrence v6: batch-split for full-chip occupancy. v5 ran 64 blocks
// (16 batch rows each) = 64 CUs busy, 192 idle, with a 31-step serial
// recurrence — latency-bound (~11k cyc/step wall vs ~2.5k issued). v6: 4
// rows/block x 256 blocks = ALL CUs. MFMA M=16 granularity means per-block
// MFMA issue is unchanged (A rows 4..15 stay zero: s_h zero-init, never
// written -> their gate rows are exact zeros, unread), but gate VALU is 1
// row/thread (was 4), xgv 4 loads (was 16), and 4x more CUs run in parallel.
// Each surviving row's MFMA chain (nt/ks/hi-lo order) and gate arithmetic
// are unchanged -> bit-identical.
// ---------------------------------------------------------------------------
#define HS 136    // s_h row stride in shorts (68 dwords = 4 mod 32)
#define GS 516    // s_g2 row stride in floats (516 = 4 mod 32, 16B-mult)

template <bool FINAL>
__launch_bounds__(512)
__global__ void lstm_mfma(const float* __restrict__ xg, const short* __restrict__ whhfG,
                          float* __restrict__ out0,
                          const float* __restrict__ Wc1, const float* __restrict__ bc1,
                          const float* __restrict__ Wc2, const float* __restrict__ bc2,
                          float* __restrict__ out) {
    __shared__ __align__(16) short s_h[16 * HS];    // h bf16 [m][k]; rows 4..15 stay 0
    __shared__ __align__(16) float s_g2[16 * GS];   // mfma gates fp32 [m][n]
    __shared__ __align__(16) float s_hid[4 * 68];
    const int tid = threadIdx.x;
    const int w = tid >> 6, l = tid & 63, quad = l >> 4, l15 = l & 15;
    const int b0 = blockIdx.x * 4;                  // 4 batch rows per block
    const int u = tid & 127, r0 = tid >> 7;         // r0 = this thread's row (0..3)

    short8 whf[16], wlf[16];
    #pragma unroll
    for (int nt = 0; nt < 4; ++nt)
        #pragma unroll
        for (int ks = 0; ks < 4; ++ks) {
            size_t NT = (size_t)(w * 4 + nt);
            whf[nt * 4 + ks] = *(const short8*)(whhfG + (((NT * 4 + ks) * 2 + 0) * 64 + l) * 8);
            wlf[nt * 4 + ks] = *(const short8*)(whhfG + (((NT * 4 + ks) * 2 + 1) * 64 + l) * 8);
        }

    float c0 = 0.f;
    for (int e = tid; e < 16 * HS; e += 512) s_h[e] = 0;
    __syncthreads();

    for (int t = 0; t < 31; ++t) {
        float xgv[4];
        {
            size_t base = ((size_t)(b0 + r0) * PNUM + t) * 512 + u;
            xgv[0] = xg[base];
            xgv[1] = xg[base + 128];
            xgv[2] = xg[base + 256];
            xgv[3] = xg[base + 384];
        }

        short8 af[4];
        #pragma unroll
        for (int ks = 0; ks < 4; ++ks)
            af[ks] = *(const short8*)&s_h[l15 * HS + ks * 32 + quad * 8];
        f32x4 z = {0.f, 0.f, 0.f, 0.f};
        f32x4 acc[4] = {z, z, z, z};
        #pragma unroll
        for (int nt = 0; nt < 4; ++nt)
            #pragma unroll
            for (int ks = 0; ks < 4; ++ks) {
                acc[nt] = MFMA16(af[ks], whf[nt * 4 + ks], acc[nt]);
                acc[nt] = MFMA16(af[ks], wlf[nt * 4 + ks], acc[nt]);
            }
        #pragma unroll
        for (int nt = 0; nt < 4; ++nt) {
            int n = w * 64 + nt * 16 + l15;
            #pragma unroll
            for (int reg = 0; reg < 4; ++reg)
                s_g2[(quad * 4 + reg) * GS + n] = acc[nt][reg];
        }
        bar_lds();

        {
            float gi = xgv[0] + s_g2[r0 * GS + u];
            float gf = xgv[1] + s_g2[r0 * GS + 128 + u];
            float gg = xgv[2] + s_g2[r0 * GS + 256 + u];
            float go = xgv[3] + s_g2[r0 * GS + 384 + u];
            float cn = sigf(gf) * c0 + sigf(gi) * tanhfast(gg);
            float h = sigf(go) * tanhfast(cn);
            c0 = cn;
            s_h[r0 * HS + u] = f2bf(h);
            if (!FINAL)
                out0[((size_t)(b0 + r0) * PNUM + t) * 128 + u] = h;
        }
        bar_lds();
    }

    if (FINAL) {
        if (tid < 256) {
            int rr = tid >> 6, uu = tid & 63;
            float acc = bc1[uu];
            const float* wv = Wc1 + (size_t)uu * 128;
            #pragma unroll 8
            for (int k = 0; k < 128; ++k) acc += wv[k] * bf2f(s_h[rr * HS + k]);
            s_hid[rr * 68 + uu] = fmaxf(acc, 0.f);
        }
        __syncthreads();
        if (tid < 44) {
            int rr = tid / 11, cc = tid % 11;
            float acc = bc2[cc];
            #pragma unroll
            for (int uu = 0; uu < 64; ++uu) acc += Wc2[cc * 64 + uu] * s_hid[rr * 68 + uu];
            out[(size_t)(b0 + rr) * 11 + cc] = acc;
        }
    }
}

// ---------------------------------------------------------------------------
extern "C" void kernel_launch(void* const* d_in, const int* in_sizes, int n_in,
                              void* d_out, int out_size, void* d_ws, size_t ws_size,
                              hipStream_t stream) {
    (void)in_sizes; (void)n_in; (void)out_size; (void)ws_size;
    const float* I    = (const float*)d_in[0];
    const float* Q    = (const float*)d_in[1];
    const float* ew   = (const float*)d_in[2];
    const float* Wn1  = (const float*)d_in[3];
    const float* bn1  = (const float*)d_in[4];
    const float* Ws1  = (const float*)d_in[5];
    const float* bs1  = (const float*)d_in[6];
    const float* Wn2  = (const float*)d_in[7];
    const float* bn2  = (const float*)d_in[8];
    const float* Ws2  = (const float*)d_in[9];
    const float* bs2  = (const float*)d_in[10];
    const float* Wih0 = (const float*)d_in[11];
    const float* Whh0 = (const float*)d_in[12];
    const float* bih0 = (const float*)d_in[13];
    const float* bhh0 = (const float*)d_in[14];
    const float* Wih1 = (const float*)d_in[15];
    const float* Whh1 = (const float*)d_in[16];
    const float* bih1 = (const float*)d_in[17];
    const float* bhh1 = (const float*)d_in[18];
    const float* Wc1  = (const float*)d_in[19];
    const float* bc1  = (const float*)d_in[20];
    const float* Wc2  = (const float*)d_in[21];
    const float* bc2  = (const float*)d_in[22];
    float* out = (float*)d_out;

    // workspace (floats): ~90.4 MB
    float* wsp   = (float*)d_ws;
    float* adjn  = wsp;                           // 4096
    float* WihT0 = adjn  + 4096;                  // 32768
    float* WihT1 = WihT0 + 32768;                 // 65536
    short* adjfG  = (short*)(WihT1 + 65536);      // 3072 shorts
    short* wcatfG = adjfG + 3072;                 // 16384 shorts
    short* whhf0G = wcatfG + 16384;               // 131072 shorts
    short* whhf1G = whhf0G + 131072;              // 131072 shorts  (=> 140800 floats total)
    float* feats = WihT1 + 65536 + 140800;        // 2031616
    float* out0  = feats + 2031616;               // 4063232
    float* xg    = out0  + 4063232;               // 16252928 (shared by both layers)

    adj_kernel<<<1, 64, 0, stream>>>(ew, adjn);
    prep_kernel<<<522, 256, 0, stream>>>(Wih0, Whh0, Wih1, Whh1, adjn, Ws2, Wn2,
                                         WihT0, WihT1, adjfG, wcatfG, whhf0G, whhf1G);
    sage_mfma<<<SGRID, 256, 0, stream>>>(I, Q, adjn, Wn1, bn1, Ws1, bs1,
                                         bn2, bs2, adjfG, wcatfG, feats);
    gemm512_kernel<64><<<dim3(496, 4), 256, 0, stream>>>(feats, WihT0, bih0, bhh0, xg);
    lstm_mfma<false><<<256, 512, 0, stream>>>(xg, whhf0G, out0,
                                              nullptr, nullptr, nullptr, nullptr, nullptr);
    gemm512_kernel<128><<<dim3(496, 4), 256, 0, stream>>>(out0, WihT1, bih1, bhh1, xg);
    lstm_mfma<true><<<256, 512, 0, stream>>>(xg, whhf1G, nullptr,
                                             Wc1, bc1, Wc2, bc2, out);
}

// Round 12
// 423.529 us; speedup vs baseline: 1.3834x; 1.1537x over previous
//
#include <hip/hip_runtime.h>
#include <hip/hip_bf16.h>
#include <math.h>

#define L_SZ 1024
#define STRIDE_ 32
#define WIN 8
#define PNUM 31
#define NPATCH 31744   // 1024 batches x 31 patches
#define SGRID 512      // 256 CU x 2 blocks/CU co-resident ((256,2)-pinned residency)

// LDS row strides (in shorts). dword strides = 36/68 = 4 mod 32 -> 2-way banks (free).
#define X1TS 72
#define CAS  136

typedef __attribute__((ext_vector_type(8))) short short8;
typedef __attribute__((ext_vector_type(4))) short short4v;
typedef __attribute__((ext_vector_type(4))) float f32x4;

#define MFMA16(a, b, c) __builtin_amdgcn_mfma_f32_16x16x32_bf16(a, b, c, 0, 0, 0)

// LDS-only barrier: waits lgkmcnt only; vmem stays in flight across the
// barrier (compiler inserts vmcnt waits before first USE of loaded values).
// sched_barrier(0) fences both sides (rule #18).
__device__ __forceinline__ void bar_lds() {
    __builtin_amdgcn_sched_barrier(0);
    asm volatile("s_waitcnt lgkmcnt(0)" ::: "memory");
    __builtin_amdgcn_s_barrier();
    __builtin_amdgcn_sched_barrier(0);
}

__device__ __forceinline__ float sigf(float x) { return 1.0f / (1.0f + __expf(-x)); }
__device__ __forceinline__ float tanhfast(float x) {
    float ax = fabsf(x);
    float t = __expf(-2.0f * ax);
    return copysignf((1.0f - t) / (1.0f + t), x);
}
__device__ __forceinline__ short f2bf(float f) {
    __hip_bfloat16 h = __float2bfloat16(f);   // RNE
    return *reinterpret_cast<short*>(&h);
}
__device__ __forceinline__ float bf2f(short s) {
    __hip_bfloat16 h = *reinterpret_cast<__hip_bfloat16*>(&s);
    return __bfloat162float(h);
}

// ---------------------------------------------------------------------------
// adjn[i][j] = sigmoid(ew[i][j]) * mask(|i-j|<=8, i!=j) * deg_inv[i]
// ---------------------------------------------------------------------------
__global__ void adj_kernel(const float* __restrict__ ew, float* __restrict__ adjn) {
    int i = threadIdx.x;
    if (i >= 64) return;
    float sum = 0.f;
    for (int j = 0; j < 64; ++j) {
        int d = i - j; d = d < 0 ? -d : d;
        float a = (d <= WIN && d != 0) ? sigf(ew[i * 64 + j]) : 0.f;
        sum += a;
    }
    float dinv = (sum > 0.f) ? 1.0f / sum : 0.f;
    for (int j = 0; j < 64; ++j) {
        int d = i - j; d = d < 0 ? -d : d;
        float a = (d <= WIN && d != 0) ? sigf(ew[i * 64 + j]) : 0.f;
        adjn[i * 64 + j] = a * dinv;
    }
}

// ---------------------------------------------------------------------------
// prep (R27): WihT fp32 transposes replaced by Wih bf16 hi/lo FRAGS (for the
// MFMA gemm), same frag convention as whhf (verified by sage MFMA#2 / lstm):
// B-frag for (nt, ks, hl): lane l -> Wih[(16nt + l&15)*K + 32ks + 8(l>>4) + e].
//   blocks   0..31  : wihf0 (K=64:  32nt x 2ks x 2hl = 128 frags)
//   blocks  32..95  : wihf1 (K=128: 32nt x 4ks x 2hl = 256 frags)
//   blocks  96..105 : sage frags | 106..169: Whh0 | 170..233: Whh1
// ---------------------------------------------------------------------------
__global__ void prep_kernel(const float* __restrict__ Wih0, const float* __restrict__ Whh0,
                            const float* __restrict__ Wih1, const float* __restrict__ Whh1,
                            const float* __restrict__ adjn,
                            const float* __restrict__ Ws2, const float* __restrict__ Wn2,
                            short* __restrict__ wihf0G, short* __restrict__ wihf1G,
                            short* __restrict__ adjfG, short* __restrict__ wcatfG,
                            short* __restrict__ whhf0G, short* __restrict__ whhf1G) {
    int bid = blockIdx.x, tid = threadIdx.x;
    if (bid < 32) {                      // wihf0: f = nt*4 + ks*2 + hl (K32=2)
        int t = bid * 256 + tid;         // 0..8191
        int f = t >> 6, l = t & 63;
        int hl = f & 1, ks = (f >> 1) & 1, nt = f >> 2;
        int q = l >> 4, l15 = l & 15;
        short8 v;
        #pragma unroll
        for (int e = 0; e < 8; ++e) {
            float src = Wih0[(size_t)(nt * 16 + l15) * 64 + ks * 32 + 8 * q + e];
            short hi = f2bf(src);
            v[e] = hl ? f2bf(src - bf2f(hi)) : hi;
        }
        *(short8*)(wihf0G + (size_t)f * 512 + l * 8) = v;
        return;
    }
    if (bid < 96) {                      // wihf1: f = nt*8 + ks*2 + hl (K32=4)
        int t = (bid - 32) * 256 + tid;  // 0..16383
        int f = t >> 6, l = t & 63;
        int hl = f & 1, ks = (f >> 1) & 3, nt = f >> 3;
        int q = l >> 4, l15 = l & 15;
        short8 v;
        #pragma unroll
        for (int e = 0; e < 8; ++e) {
            float src = Wih1[(size_t)(nt * 16 + l15) * 128 + ks * 32 + 8 * q + e];
            short hi = f2bf(src);
            v[e] = hl ? f2bf(src - bf2f(hi)) : hi;
        }
        *(short8*)(wihf1G + (size_t)f * 512 + l * 8) = v;
        return;
    }
    if (bid < 106) {
        int t = (bid - 96) * 256 + tid;
        if (t >= 2432) return;
        int f = t >> 6, l = t & 63;
        int q = l >> 4, l15 = l & 15;
        short8 v;
        if (f < 6) {
            const int ntT[6] = {0, 1, 1, 2, 2, 3};
            const int ksT[6] = {0, 0, 1, 0, 1, 1};
            int row = l15 + 16 * ntT[f], col = 8 * q + 32 * ksT[f];
            #pragma unroll
            for (int e = 0; e < 8; ++e)
                v[e] = f2bf(adjn[row * 64 + col + e]);
            *(short8*)(adjfG + ((size_t)f * 64 + l) * 8) = v;
        } else {
            int fi = f - 6;
            int isLo = fi >= 16;
            int ff = isLo ? fi - 16 : fi;
            int nt = ff >> 2, ks = ff & 3;
            int oo = l15 + 16 * nt;
            #pragma unroll
            for (int e = 0; e < 8; ++e) {
                int k = 32 * ks + 8 * q + e;
                float src = (k < 64) ? Ws2[oo * 64 + k] : Wn2[oo * 64 + (k - 64)];
                short hi = f2bf(src);
                v[e] = isLo ? f2bf(src - bf2f(hi)) : hi;
            }
            *(short8*)(wcatfG + ((size_t)fi * 64 + l) * 8) = v;
        }
        return;
    }
    {
        int layer = (bid < 170) ? 0 : 1;
        int base = layer ? 170 : 106;
        const float* Whh = layer ? Whh1 : Whh0;
        short* dst = layer ? whhf1G : whhf0G;
        int t = (bid - base) * 256 + tid;    // 0..16383
        int frag = t >> 6, l = t & 63;
        int hl = frag & 1, ks = (frag >> 1) & 3, NT = frag >> 3;
        int g = NT * 16 + (l & 15);
        int kbase = ks * 32 + (l >> 4) * 8;
        short8 v;
        #pragma unroll
        for (int e = 0; e < 8; ++e) {
            float src = Whh[(size_t)g * 128 + kbase + e];
            short hi = f2bf(src);
            v[e] = hl ? f2bf(src - bf2f(hi)) : hi;
        }
        *(short8*)(dst + (size_t)t * 8) = v;
    }
}

// ---------------------------------------------------------------------------
// Persistent fused SAGE, bf16 MFMA. (R25 structure — plateau 180 us; control.)
// ---------------------------------------------------------------------------
__launch_bounds__(256, 2)
__global__ void sage_mfma(const float* __restrict__ I, const float* __restrict__ Q,
                          const float* __restrict__ adjn,
                          const float* __restrict__ Wn1, const float* __restrict__ bn1,
                          const float* __restrict__ Ws1, const float* __restrict__ bs1,
                          const float* __restrict__ bn2, const float* __restrict__ bs2,
                          const short* __restrict__ adjfG, const short* __restrict__ wcatfG,
                          float* __restrict__ feats) {
    __shared__ __align__(16) short s_x1T[2][64 * X1TS];  // x1^T [o][i] bf16, per patch
    __shared__ __align__(16) short s_cat[2][64 * CAS];   // [i][x1|n1] bf16, per patch

    const int tid = threadIdx.x;
    const int w = tid >> 6, l = tid & 63, q = l >> 4, l15 = l & 15;

    const bool hasKs0 = (w <= 2);
    const bool hasKs1 = (w >= 1);
    const int idx0 = (w == 0) ? 0 : (w == 1 ? 1 : 3);
    const int idx1 = (w == 1) ? 2 : (w == 2 ? 4 : 5);
    short8 adjB0 = {}, adjB1 = {};
    if (hasKs0) adjB0 = *(const short8*)(adjfG + ((size_t)idx0 * 64 + l) * 8);
    if (hasKs1) adjB1 = *(const short8*)(adjfG + ((size_t)idx1 * 64 + l) * 8);

    short8 whf[4], wlf[4];
    #pragma unroll
    for (int ks = 0; ks < 4; ++ks) {
        whf[ks] = *(const short8*)(wcatfG + ((size_t)(w * 4 + ks) * 64 + l) * 8);
        wlf[ks] = *(const short8*)(wcatfG + ((size_t)(w * 4 + ks + 16) * 64 + l) * 8);
    }
    const int oo = l15 + 16 * w;
    const float bo = bs2[oo] + bn2[oo];

    float areg[17];
    #pragma unroll
    for (int d = 0; d < 17; ++d) {
        int j = l + d - WIN;
        areg[d] = (j >= 0 && j < 64) ? adjn[l * 64 + j] : 0.f;
    }

    float x0a[2], x0b[2];
    #pragma unroll
    for (int P = 0; P < 2; ++P) {
        int m = blockIdx.x + P * 512;
        int b = m / PNUM, p = m % PNUM;
        x0a[P] = I[(size_t)b * L_SZ + p * STRIDE_ + l];
        x0b[P] = Q[(size_t)b * L_SZ + p * STRIDE_ + l];
    }

    for (int it = 0; it < 31; ++it) {
        const int m0 = it * 1024 + blockIdx.x;

        #pragma unroll
        for (int P = 0; P < 2; ++P) {
            float n0a = 0.f, n0b = 0.f;
            #pragma unroll
            for (int d = 0; d < 17; ++d) {
                int j = l + d - WIN;
                float xa = __shfl(x0a[P], j, 64);
                float xb = __shfl(x0b[P], j, 64);
                n0a += areg[d] * xa;
                n0b += areg[d] * xb;
            }
            union { short s[16]; short8 v[2]; } pk;
            #pragma unroll
            for (int t = 0; t < 16; ++t) {
                int o = w * 16 + t;
                float2 wsv = ((const float2*)Ws1)[o];
                float2 wnv = ((const float2*)Wn1)[o];
                float v = bs1[o] + bn1[o] + wsv.x * x0a[P] + wsv.y * x0b[P]
                                          + wnv.x * n0a + wnv.y * n0b;
                v = fmaxf(v, 0.f);
                short bv = f2bf(v);
                s_x1T[P][o * X1TS + l] = bv;
                pk.s[t] = bv;
            }
            *(short8*)&s_cat[P][l * CAS + w * 16]     = pk.v[0];
            *(short8*)&s_cat[P][l * CAS + w * 16 + 8] = pk.v[1];
        }

        if (it + 1 < 31) {
            #pragma unroll
            for (int P = 0; P < 2; ++P) {
                int m = (it + 1) * 1024 + blockIdx.x + P * 512;
                int b = m / PNUM, p = m % PNUM;
                x0a[P] = I[(size_t)b * L_SZ + p * STRIDE_ + l];
                x0b[P] = Q[(size_t)b * L_SZ + p * STRIDE_ + l];
            }
        }
        bar_lds();

        #pragma unroll
        for (int P = 0; P < 2; ++P) {
            #pragma unroll
            for (int ot = 0; ot < 4; ++ot) {
                f32x4 c = {0.f, 0.f, 0.f, 0.f};
                if (hasKs0) {
                    short8 a = *(const short8*)&s_x1T[P][(16 * ot + l15) * X1TS + 8 * q];
                    c = MFMA16(a, adjB0, c);
                }
                if (hasKs1) {
                    short8 a = *(const short8*)&s_x1T[P][(16 * ot + l15) * X1TS + 8 * q + 32];
                    c = MFMA16(a, adjB1, c);
                }
                short4v nv;
                nv[0] = f2bf(c[0]); nv[1] = f2bf(c[1]);
                nv[2] = f2bf(c[2]); nv[3] = f2bf(c[3]);
                *(short4v*)&s_cat[P][(16 * w + l15) * CAS + 64 + 16 * ot + 4 * q] = nv;
            }
        }
        bar_lds();

        #pragma unroll
        for (int P = 0; P < 2; ++P) {
            f32x4 z = {0.f, 0.f, 0.f, 0.f};
            f32x4 acc2[4] = {z, z, z, z};
            #pragma unroll
            for (int it2 = 0; it2 < 4; ++it2) {
                short8 a2[4];
                #pragma unroll
                for (int ks = 0; ks < 4; ++ks)
                    a2[ks] = *(const short8*)&s_cat[P][(16 * it2 + l15) * CAS + 32 * ks + 8 * q];
                #pragma unroll
                for (int ks = 0; ks < 4; ++ks) {
                    acc2[it2] = MFMA16(a2[ks], whf[ks], acc2[it2]);
                    acc2[it2] = MFMA16(a2[ks], wlf[ks], acc2[it2]);
                }
            }
            float total = 0.f;
            #pragma unroll
            for (int it2 = 0; it2 < 4; ++it2) {
                float s = fmaxf(acc2[it2][0] + bo, 0.f) + fmaxf(acc2[it2][1] + bo, 0.f)
                        + fmaxf(acc2[it2][2] + bo, 0.f) + fmaxf(acc2[it2][3] + bo, 0.f);
                s += __shfl_xor(s, 16);
                s += __shfl_xor(s, 32);
                total += s;
            }
            if (l < 16)
                feats[(size_t)(m0 + P * 512) * 64 + 16 * w + l15] = total;
        }
        bar_lds();
    }
}

// ---------------------------------------------------------------------------
// GEMM v2 (R27): MFMA with double-bf16 (hi/lo) on BOTH operands, 3-term
// product (ah*bh + al*bh + ah*bl; al*bl ~2^-32 dropped). Moves ~6.3 GFLOP
// off the fp32 VALU (no fp32 MFMA on CDNA4) onto the matrix pipe; kernel
// becomes memory-bound on the 65 MB xg write. Error ~K*2^-17*|ab| ~1e-4,
// sigmoid/tanh-attenuated downstream. Fragment convention identical to the
// verified sage MFMA#2 / lstm path (A: lane=m l15, k=32ks+8q+e; B from prep
// frags; C: col=l15, row=4q+reg). C[M x 512] = A[M x K] @ Wih^T + b1 + b2.
// ---------------------------------------------------------------------------
template <int K>
__launch_bounds__(256, 2)
__global__ void gemm_mfma(const float* __restrict__ A, const short* __restrict__ wihfG,
                          const float* __restrict__ bias1, const float* __restrict__ bias2,
                          float* __restrict__ C) {
    constexpr int K32 = K / 32;
    constexpr int K4 = K / 4;
    constexpr int AS = (K == 64) ? 72 : 136;   // row stride in shorts (4-mod-32 dwords)
    __shared__ __align__(16) short s_ah[64 * AS];
    __shared__ __align__(16) short s_al[64 * AS];
    const int tid = threadIdx.x;
    const int w = tid >> 6, l = tid & 63, q = l >> 4, l15 = l & 15;
    const int m0 = blockIdx.x * 64;
    const int j0 = blockIdx.y * 128;

    // stage A hi/lo into LDS (64 rows x K floats -> 2x bf16)
    {
        const float4* Ag = (const float4*)(A + (size_t)m0 * K);
        for (int e = tid; e < 16 * K; e += 256) {
            int row = e / K4, c4 = e % K4;
            float4 v = Ag[row * K4 + c4];
            short4v h, lo;
            h[0] = f2bf(v.x); lo[0] = f2bf(v.x - bf2f(h[0]));
            h[1] = f2bf(v.y); lo[1] = f2bf(v.y - bf2f(h[1]));
            h[2] = f2bf(v.z); lo[2] = f2bf(v.z - bf2f(h[2]));
            h[3] = f2bf(v.w); lo[3] = f2bf(v.w - bf2f(h[3]));
            *(short4v*)&s_ah[row * AS + c4 * 4] = h;
            *(short4v*)&s_al[row * AS + c4 * 4] = lo;
        }
    }

    // B frags: wave w owns global ntiles (j0/16 + 2w) and (j0/16 + 2w + 1)
    short8 bh[2][K32], bl[2][K32];
    #pragma unroll
    for (int c = 0; c < 2; ++c) {
        int nt = (j0 >> 4) + 2 * w + c;
        #pragma unroll
        for (int ks = 0; ks < K32; ++ks) {
            bh[c][ks] = *(const short8*)(wihfG + (((size_t)(nt * K32 + ks) * 2 + 0) * 64 + l) * 8);
            bl[c][ks] = *(const short8*)(wihfG + (((size_t)(nt * K32 + ks) * 2 + 1) * 64 + l) * 8);
        }
    }
    __syncthreads();

    f32x4 z = {0.f, 0.f, 0.f, 0.f};
    #pragma unroll
    for (int mt = 0; mt < 4; ++mt) {
        f32x4 acc[2] = {z, z};
        #pragma unroll
        for (int ks = 0; ks < K32; ++ks) {
            short8 ah = *(const short8*)&s_ah[(16 * mt + l15) * AS + 32 * ks + 8 * q];
            short8 al = *(const short8*)&s_al[(16 * mt + l15) * AS + 32 * ks + 8 * q];
            #pragma unroll
            for (int c = 0; c < 2; ++c) {
                acc[c] = MFMA16(ah, bh[c][ks], acc[c]);
                acc[c] = MFMA16(al, bh[c][ks], acc[c]);
                acc[c] = MFMA16(ah, bl[c][ks], acc[c]);
            }
        }
        #pragma unroll
        for (int c = 0; c < 2; ++c) {
            int col = j0 + (2 * w + c) * 16 + l15;
            float bo = bias1[col] + bias2[col];
            #pragma unroll
            for (int reg = 0; reg < 4; ++reg) {
                int row = m0 + 16 * mt + 4 * q + reg;
                C[(size_t)row * 512 + col] = acc[c][reg] + bo;
            }
        }
    }
}

// ---------------------------------------------------------------------------
// LSTM recurrence v7: v6 (4 rows/block x 256 blocks) + cross-step xgv
// prefetch: loads for step t+1 issue BEFORE the first bar_lds of step t, so
// (with the LDS-only barrier) they stay in flight through barrier + gate +
// next MFMA phase (~600 cyc) instead of exposing HBM latency at step top.
// Math unchanged -> bit-identical to v6.
// ---------------------------------------------------------------------------
#define HS 136    // s_h row stride in shorts (68 dwords = 4 mod 32)
#define GS 516    // s_g2 row stride in floats (516 = 4 mod 32, 16B-mult)

template <bool FINAL>
__launch_bounds__(512)
__global__ void lstm_mfma(const float* __restrict__ xg, const short* __restrict__ whhfG,
                          float* __restrict__ out0,
                          const float* __restrict__ Wc1, const float* __restrict__ bc1,
                          const float* __restrict__ Wc2, const float* __restrict__ bc2,
                          float* __restrict__ out) {
    __shared__ __align__(16) short s_h[16 * HS];    // h bf16 [m][k]; rows 4..15 stay 0
    __shared__ __align__(16) float s_g2[16 * GS];   // mfma gates fp32 [m][n]
    __shared__ __align__(16) float s_hid[4 * 68];
    const int tid = threadIdx.x;
    const int w = tid >> 6, l = tid & 63, quad = l >> 4, l15 = l & 15;
    const int b0 = blockIdx.x * 4;                  // 4 batch rows per block
    const int u = tid & 127, r0 = tid >> 7;         // r0 = this thread's row (0..3)

    short8 whf[16], wlf[16];
    #pragma unroll
    for (int nt = 0; nt < 4; ++nt)
        #pragma unroll
        for (int ks = 0; ks < 4; ++ks) {
            size_t NT = (size_t)(w * 4 + nt);
            whf[nt * 4 + ks] = *(const short8*)(whhfG + (((NT * 4 + ks) * 2 + 0) * 64 + l) * 8);
            wlf[nt * 4 + ks] = *(const short8*)(whhfG + (((NT * 4 + ks) * 2 + 1) * 64 + l) * 8);
        }

    float c0 = 0.f;
    for (int e = tid; e < 16 * HS; e += 512) s_h[e] = 0;
    __syncthreads();

    // prefetch t=0 xgv
    float xgv[4];
    {
        size_t base = ((size_t)(b0 + r0) * PNUM + 0) * 512 + u;
        xgv[0] = xg[base];
        xgv[1] = xg[base + 128];
        xgv[2] = xg[base + 256];
        xgv[3] = xg[base + 384];
    }

    for (int t = 0; t < 31; ++t) {
        short8 af[4];
        #pragma unroll
        for (int ks = 0; ks < 4; ++ks)
            af[ks] = *(const short8*)&s_h[l15 * HS + ks * 32 + quad * 8];
        f32x4 z = {0.f, 0.f, 0.f, 0.f};
        f32x4 acc[4] = {z, z, z, z};
        #pragma unroll
        for (int nt = 0; nt < 4; ++nt)
            #pragma unroll
            for (int ks = 0; ks < 4; ++ks) {
                acc[nt] = MFMA16(af[ks], whf[nt * 4 + ks], acc[nt]);
                acc[nt] = MFMA16(af[ks], wlf[nt * 4 + ks], acc[nt]);
            }
        #pragma unroll
        for (int nt = 0; nt < 4; ++nt) {
            int n = w * 64 + nt * 16 + l15;
            #pragma unroll
            for (int reg = 0; reg < 4; ++reg)
                s_g2[(quad * 4 + reg) * GS + n] = acc[nt][reg];
        }

        // issue next-step xgv loads: in flight across bar_lds + gate phase
        float nx0 = 0.f, nx1 = 0.f, nx2 = 0.f, nx3 = 0.f;
        if (t + 1 < 31) {
            size_t base = ((size_t)(b0 + r0) * PNUM + (t + 1)) * 512 + u;
            nx0 = xg[base];
            nx1 = xg[base + 128];
            nx2 = xg[base + 256];
            nx3 = xg[base + 384];
        }
        bar_lds();

        {
            float gi = xgv[0] + s_g2[r0 * GS + u];
            float gf = xgv[1] + s_g2[r0 * GS + 128 + u];
            float gg = xgv[2] + s_g2[r0 * GS + 256 + u];
            float go = xgv[3] + s_g2[r0 * GS + 384 + u];
            float cn = sigf(gf) * c0 + sigf(gi) * tanhfast(gg);
            float h = sigf(go) * tanhfast(cn);
            c0 = cn;
            s_h[r0 * HS + u] = f2bf(h);
            if (!FINAL)
                out0[((size_t)(b0 + r0) * PNUM + t) * 128 + u] = h;
        }
        xgv[0] = nx0; xgv[1] = nx1; xgv[2] = nx2; xgv[3] = nx3;
        bar_lds();
    }

    if (FINAL) {
        if (tid < 256) {
            int rr = tid >> 6, uu = tid & 63;
            float acc = bc1[uu];
            const float* wv = Wc1 + (size_t)uu * 128;
            #pragma unroll 8
            for (int k = 0; k < 128; ++k) acc += wv[k] * bf2f(s_h[rr * HS + k]);
            s_hid[rr * 68 + uu] = fmaxf(acc, 0.f);
        }
        __syncthreads();
        if (tid < 44) {
            int rr = tid / 11, cc = tid % 11;
            float acc = bc2[cc];
            #pragma unroll
            for (int uu = 0; uu < 64; ++uu) acc += Wc2[cc * 64 + uu] * s_hid[rr * 68 + uu];
            out[(size_t)(b0 + rr) * 11 + cc] = acc;
        }
    }
}

// ---------------------------------------------------------------------------
extern "C" void kernel_launch(void* const* d_in, const int* in_sizes, int n_in,
                              void* d_out, int out_size, void* d_ws, size_t ws_size,
                              hipStream_t stream) {
    (void)in_sizes; (void)n_in; (void)out_size; (void)ws_size;
    const float* I    = (const float*)d_in[0];
    const float* Q    = (const float*)d_in[1];
    const float* ew   = (const float*)d_in[2];
    const float* Wn1  = (const float*)d_in[3];
    const float* bn1  = (const float*)d_in[4];
    const float* Ws1  = (const float*)d_in[5];
    const float* bs1  = (const float*)d_in[6];
    const float* Wn2  = (const float*)d_in[7];
    const float* bn2  = (const float*)d_in[8];
    const float* Ws2  = (const float*)d_in[9];
    const float* bs2  = (const float*)d_in[10];
    const float* Wih0 = (const float*)d_in[11];
    const float* Whh0 = (const float*)d_in[12];
    const float* bih0 = (const float*)d_in[13];
    const float* bhh0 = (const float*)d_in[14];
    const float* Wih1 = (const float*)d_in[15];
    const float* Whh1 = (const float*)d_in[16];
    const float* bih1 = (const float*)d_in[17];
    const float* bhh1 = (const float*)d_in[18];
    const float* Wc1  = (const float*)d_in[19];
    const float* bc1  = (const float*)d_in[20];
    const float* Wc2  = (const float*)d_in[21];
    const float* bc2  = (const float*)d_in[22];
    float* out = (float*)d_out;

    // workspace (floats): ~90.4 MB. wihf0G/wihf1G occupy the old WihT0/WihT1
    // slots byte-for-byte (65536 shorts = 32768 floats; 131072 = 65536).
    float* wsp   = (float*)d_ws;
    float* adjn  = wsp;                           // 4096
    short* wihf0G = (short*)(adjn + 4096);        // 65536 shorts  (32768 floats)
    short* wihf1G = (short*)(adjn + 4096 + 32768);// 131072 shorts (65536 floats)
    short* adjfG  = (short*)(adjn + 4096 + 98304);// 3072 shorts
    short* wcatfG = adjfG + 3072;                 // 16384 shorts
    short* whhf0G = wcatfG + 16384;               // 131072 shorts
    short* whhf1G = whhf0G + 131072;              // 131072 shorts  (=> 140800 floats total)
    float* feats = adjn + 4096 + 98304 + 140800;  // 2031616
    float* out0  = feats + 2031616;               // 4063232
    float* xg    = out0  + 4063232;               // 16252928 (shared by both layers)

    adj_kernel<<<1, 64, 0, stream>>>(ew, adjn);
    prep_kernel<<<234, 256, 0, stream>>>(Wih0, Whh0, Wih1, Whh1, adjn, Ws2, Wn2,
                                         wihf0G, wihf1G, adjfG, wcatfG, whhf0G, whhf1G);
    sage_mfma<<<SGRID, 256, 0, stream>>>(I, Q, adjn, Wn1, bn1, Ws1, bs1,
                                         bn2, bs2, adjfG, wcatfG, feats);
    gemm_mfma<64><<<dim3(496, 4), 256, 0, stream>>>(feats, wihf0G, bih0, bhh0, xg);
    lstm_mfma<false><<<256, 512, 0, stream>>>(xg, whhf0G, out0,
                                              nullptr, nullptr, nullptr, nullptr, nullptr);
    gemm_mfma<128><<<dim3(496, 4), 256, 0, stream>>>(out0, wihf1G, bih1, bhh1, xg);
    lstm_mfma<true><<<256, 512, 0, stream>>>(xg, whhf1G, nullptr,
                                             Wc1, bc1, Wc2, bc2, out);
}